// Round 1
// baseline (1347.427 us; speedup 1.0000x reference)
//
#include <hip/hip_runtime.h>
#include <cstdint>
#include <cstddef>

#define TT 2048
#define DD 1024
#define FF 2048
#define NG 16
#define CAP (TT*4)
#define EPSV 1e-5f

typedef __attribute__((ext_vector_type(8))) short short8;
typedef __attribute__((ext_vector_type(4))) float floatx4;

__device__ inline unsigned short f2bf(float f) {
  union { float f; unsigned int u; } v; v.f = f;
  unsigned int r = v.u + 0x7fffu + ((v.u >> 16) & 1u);
  return (unsigned short)(r >> 16);
}

// ---------------- routing ----------------
__global__ __launch_bounds__(256) void k_route(
    const float* __restrict__ xf, const float* __restrict__ Wrc,
    const float* __restrict__ brc, const float* __restrict__ Wre,
    const float* __restrict__ bre, float* __restrict__ gate,
    float* __restrict__ coefs, float* __restrict__ tstats,
    int* __restrict__ counts)
{
  int t = blockIdx.x;
  const float* xr = xf + (size_t)t * DD;
  float v[22];
#pragma unroll
  for (int i = 0; i < 22; i++) v[i] = 0.f;
  for (int d = threadIdx.x; d < DD; d += 256) {
    float x = xr[d];
    v[20] += x; v[21] += x * x;
    float4 wc = *(const float4*)(Wrc + (size_t)d * 4);
    v[0] += x * wc.x; v[1] += x * wc.y; v[2] += x * wc.z; v[3] += x * wc.w;
#pragma unroll
    for (int c = 0; c < 4; c++) {
      float4 we = *(const float4*)(Wre + ((size_t)c * DD + d) * 4);
      v[4 + c*4 + 0] += x * we.x; v[4 + c*4 + 1] += x * we.y;
      v[4 + c*4 + 2] += x * we.z; v[4 + c*4 + 3] += x * we.w;
    }
  }
#pragma unroll
  for (int m = 32; m >= 1; m >>= 1)
#pragma unroll
    for (int i = 0; i < 22; i++) v[i] += __shfl_xor(v[i], m);
  __shared__ float red[4][22];
  int wave = threadIdx.x >> 6, lane = threadIdx.x & 63;
  if (lane == 0) for (int i = 0; i < 22; i++) red[wave][i] = v[i];
  __syncthreads();
  if (threadIdx.x == 0) {
    for (int i = 0; i < 22; i++) v[i] = red[0][i] + red[1][i] + red[2][i] + red[3][i];
    float mean = v[20] / DD;
    float var  = v[21] / DD - mean * mean;
    tstats[t*2]   = mean;
    tstats[t*2+1] = rsqrtf(var + EPSV);
    // cluster softmax + top2 (renormalized)
    float p[4]; float mx = -1e30f;
    for (int c = 0; c < 4; c++) { v[c] += brc[c]; mx = fmaxf(mx, v[c]); }
    for (int c = 0; c < 4; c++) p[c] = expf(v[c] - mx);
    int c0 = 0;
    for (int c = 1; c < 4; c++) if (p[c] > p[c0]) c0 = c;
    int c1 = (c0 == 0) ? 1 : 0;
    for (int c = 0; c < 4; c++) if (c != c0 && p[c] > p[c1]) c1 = c;
    float ws = p[c0] + p[c1];
    gate[t*4 + c0] = p[c0] / ws;
    gate[t*4 + c1] = p[c1] / ws;
    int sels[2] = {c0, c1};
    for (int si = 0; si < 2; si++) {
      int c = sels[si];
      float l[4];
      for (int e = 0; e < 4; e++) l[e] = v[4 + c*4 + e] + bre[c*4 + e];
      int e0 = 0;
      for (int e = 1; e < 4; e++) if (l[e] > l[e0]) e0 = e;
      int e1 = (e0 == 0) ? 1 : 0;
      for (int e = 0; e < 4; e++) if (e != e0 && l[e] > l[e1]) e1 = e;
      float q1 = expf(l[e1] - l[e0]);   // l[e0] is max
      float r0 = 1.f / (1.f + q1);
      float r1 = q1 / (1.f + q1);
      if (r0 > 0.f) { coefs[t*16 + c*4 + e0] = r0; atomicAdd(&counts[c*4 + e0], 1); }
      if (r1 > 0.f) { coefs[t*16 + c*4 + e1] = r1; atomicAdd(&counts[c*4 + e1], 1); }
    }
  }
}

__global__ void k_offsets(const int* __restrict__ counts, int* __restrict__ offs) {
  if (threadIdx.x == 0 && blockIdx.x == 0) {
    int s = 0;
    for (int i = 0; i < NG; i++) { offs[i] = s; s += counts[i]; }
    offs[NG] = s;
  }
}

__global__ __launch_bounds__(256) void k_fill(
    const float* __restrict__ coefs, const int* __restrict__ offs,
    int* __restrict__ cursor, int* __restrict__ slot_token, int* __restrict__ inv_slot)
{
  int idx = blockIdx.x * 256 + threadIdx.x;
  if (idx >= TT * NG) return;
  int t = idx >> 4, ce = idx & 15;
  if (coefs[idx] > 0.f) {
    int pos = atomicAdd(&cursor[ce], 1);
    int s = offs[ce] + pos;
    slot_token[s] = t;
    inv_slot[idx] = s;
  }
}

// ---------------- gather + LN_in -> bf16 ----------------
__global__ __launch_bounds__(256) void k_gather(
    const float* __restrict__ xf, const float* __restrict__ tstats,
    const float* __restrict__ lin_g, const float* __restrict__ lin_b,
    const int* __restrict__ offs, const int* __restrict__ slot_token,
    unsigned short* __restrict__ Xg)
{
  int s = blockIdx.x;
  if (s >= offs[NG]) return;
  int g = 0;
  while (g < NG - 1 && s >= offs[g + 1]) g++;
  int t = slot_token[s];
  float mean = tstats[t*2], rstd = tstats[t*2+1];
  int d = threadIdx.x * 4;
  float4 x  = *(const float4*)(xf + (size_t)t*DD + d);
  float4 gg = *(const float4*)(lin_g + (size_t)g*DD + d);
  float4 bb = *(const float4*)(lin_b + (size_t)g*DD + d);
  ushort4 o;
  o.x = f2bf((x.x - mean)*rstd*gg.x + bb.x);
  o.y = f2bf((x.y - mean)*rstd*gg.y + bb.y);
  o.z = f2bf((x.z - mean)*rstd*gg.z + bb.z);
  o.w = f2bf((x.w - mean)*rstd*gg.w + bb.w);
  *(ushort4*)(Xg + (size_t)s*DD + d) = o;
}

// ---------------- GEMM1: Xg @ W1 (+W2) -> act -> H (bf16) ----------------
template<bool DUAL>
__global__ __launch_bounds__(256) void k_gemm1(
    const unsigned short* __restrict__ Xg, const float* __restrict__ W1,
    const float* __restrict__ W2, const int* __restrict__ counts,
    const int* __restrict__ offs, unsigned short* __restrict__ H)
{
  int z = blockIdx.z;
  int c = z >> 1;
  int e = DUAL ? ((z & 1) ? 3 : 0) : ((z & 1) + 1);
  int g = c * 4 + e;
  int count = counts[g];
  int M0 = blockIdx.x * 128;
  if (M0 >= count) return;
  int n0 = blockIdx.y * 128;
  constexpr int NB = DUAL ? 2 : 1;
  __shared__ unsigned short Al[128 * 40];
  __shared__ unsigned short Bl[NB][128 * 40];
  const unsigned short* Abase = Xg + (size_t)(offs[g] + M0) * DD;
  const float* W1g = W1 + (size_t)g * DD * FF;
  const float* W2g = W2 + (size_t)g * DD * FF;
  floatx4 zero4 = {0.f, 0.f, 0.f, 0.f};
  floatx4 acc[4][4], acc2[4][4];
#pragma unroll
  for (int i = 0; i < 4; i++)
#pragma unroll
    for (int j = 0; j < 4; j++) { acc[i][j] = zero4; acc2[i][j] = zero4; }
  int tid = threadIdx.x;
  int arow = tid >> 1, aseg = (tid & 1) << 4;
  bool aval = (M0 + arow) < count;
  int kg = tid >> 5, ng = tid & 31;
  int lane = tid & 63, wv = tid >> 6;
  int m16 = lane & 15, quad = lane >> 4;
  int wrow = (wv >> 1) * 64, wcol = (wv & 1) * 64;
  for (int k0 = 0; k0 < DD; k0 += 32) {
    { // stage A
      unsigned short* dst = Al + arow * 40 + aseg;
      if (aval) {
        const unsigned short* src = Abase + (size_t)arow * DD + k0 + aseg;
        *(int4*)dst = *(const int4*)src;
        *(int4*)(dst + 8) = *(const int4*)(src + 8);
      } else {
        int4 zz{0, 0, 0, 0};
        *(int4*)dst = zz; *(int4*)(dst + 8) = zz;
      }
    }
    // stage B (transpose + cvt)
#pragma unroll
    for (int wsel = 0; wsel < NB; wsel++) {
      const float* W = wsel ? W2g : W1g;
      const float* base = W + (size_t)(k0 + kg*4) * FF + n0 + ng*4;
      float4 r0 = *(const float4*)(base);
      float4 r1 = *(const float4*)(base + FF);
      float4 r2 = *(const float4*)(base + 2*FF);
      float4 r3 = *(const float4*)(base + 3*FF);
      unsigned short* Bp = Bl[wsel] + (ng*4)*40 + kg*4;
      ushort4 cc;
      cc.x=f2bf(r0.x); cc.y=f2bf(r1.x); cc.z=f2bf(r2.x); cc.w=f2bf(r3.x); *(ushort4*)(Bp      ) = cc;
      cc.x=f2bf(r0.y); cc.y=f2bf(r1.y); cc.z=f2bf(r2.y); cc.w=f2bf(r3.y); *(ushort4*)(Bp +  40) = cc;
      cc.x=f2bf(r0.z); cc.y=f2bf(r1.z); cc.z=f2bf(r2.z); cc.w=f2bf(r3.z); *(ushort4*)(Bp +  80) = cc;
      cc.x=f2bf(r0.w); cc.y=f2bf(r1.w); cc.z=f2bf(r2.w); cc.w=f2bf(r3.w); *(ushort4*)(Bp + 120) = cc;
    }
    __syncthreads();
    short8 af[4], b0[4], b1[4];
#pragma unroll
    for (int mi = 0; mi < 4; mi++)
      af[mi] = *(const short8*)(Al + (wrow + mi*16 + m16)*40 + quad*8);
#pragma unroll
    for (int ni = 0; ni < 4; ni++) {
      b0[ni] = *(const short8*)(Bl[0] + (wcol + ni*16 + m16)*40 + quad*8);
      if constexpr (DUAL) b1[ni] = *(const short8*)(Bl[NB-1] + (wcol + ni*16 + m16)*40 + quad*8);
    }
    __syncthreads();
#pragma unroll
    for (int mi = 0; mi < 4; mi++)
#pragma unroll
      for (int ni = 0; ni < 4; ni++) {
        acc[mi][ni] = __builtin_amdgcn_mfma_f32_16x16x32_bf16(af[mi], b0[ni], acc[mi][ni], 0, 0, 0);
        if constexpr (DUAL)
          acc2[mi][ni] = __builtin_amdgcn_mfma_f32_16x16x32_bf16(af[mi], b1[ni], acc2[mi][ni], 0, 0, 0);
      }
  }
  size_t Hbase = (size_t)(offs[g] + M0) * FF;
#pragma unroll
  for (int mi = 0; mi < 4; mi++)
#pragma unroll
    for (int ni = 0; ni < 4; ni++)
#pragma unroll
      for (int r = 0; r < 4; r++) {
        int row = wrow + mi*16 + quad*4 + r;
        if (M0 + row < count) {
          int col = n0 + wcol + ni*16 + m16;
          float h1 = acc[mi][ni][r];
          float h;
          if constexpr (DUAL) {
            float h2 = acc2[mi][ni][r];
            float sil = h2 / (1.f + expf(-h2));   // silu(h2)
            h = sil * h2 * h1;
          } else {
            if (e == 1) h = 0.5f * h1 * (1.f + erff(h1 * 0.70710678118f)); // exact gelu
            else        h = fmaxf(h1, 0.f);
          }
          H[Hbase + (size_t)row * FF + col] = f2bf(h);
        }
      }
}

// ---------------- GEMM2: H @ W3 -> Y (fp32) ----------------
__global__ __launch_bounds__(256) void k_gemm2(
    const unsigned short* __restrict__ H, const float* __restrict__ W3,
    const int* __restrict__ counts, const int* __restrict__ offs,
    float* __restrict__ Y)
{
  int g = blockIdx.z;
  int count = counts[g];
  int M0 = blockIdx.x * 128;
  if (M0 >= count) return;
  int n0 = blockIdx.y * 128;
  __shared__ unsigned short Al[128 * 40];
  __shared__ unsigned short Bl[128 * 40];
  const unsigned short* Abase = H + (size_t)(offs[g] + M0) * FF;
  const float* Wg = W3 + (size_t)g * FF * DD;
  floatx4 zero4 = {0.f, 0.f, 0.f, 0.f};
  floatx4 acc[4][4];
#pragma unroll
  for (int i = 0; i < 4; i++)
#pragma unroll
    for (int j = 0; j < 4; j++) acc[i][j] = zero4;
  int tid = threadIdx.x;
  int arow = tid >> 1, aseg = (tid & 1) << 4;
  bool aval = (M0 + arow) < count;
  int kg = tid >> 5, ng = tid & 31;
  int lane = tid & 63, wv = tid >> 6;
  int m16 = lane & 15, quad = lane >> 4;
  int wrow = (wv >> 1) * 64, wcol = (wv & 1) * 64;
  for (int k0 = 0; k0 < FF; k0 += 32) {
    {
      unsigned short* dst = Al + arow * 40 + aseg;
      if (aval) {
        const unsigned short* src = Abase + (size_t)arow * FF + k0 + aseg;
        *(int4*)dst = *(const int4*)src;
        *(int4*)(dst + 8) = *(const int4*)(src + 8);
      } else {
        int4 zz{0, 0, 0, 0};
        *(int4*)dst = zz; *(int4*)(dst + 8) = zz;
      }
    }
    {
      const float* base = Wg + (size_t)(k0 + kg*4) * DD + n0 + ng*4;
      float4 r0 = *(const float4*)(base);
      float4 r1 = *(const float4*)(base + DD);
      float4 r2 = *(const float4*)(base + 2*DD);
      float4 r3 = *(const float4*)(base + 3*DD);
      unsigned short* Bp = Bl + (ng*4)*40 + kg*4;
      ushort4 cc;
      cc.x=f2bf(r0.x); cc.y=f2bf(r1.x); cc.z=f2bf(r2.x); cc.w=f2bf(r3.x); *(ushort4*)(Bp      ) = cc;
      cc.x=f2bf(r0.y); cc.y=f2bf(r1.y); cc.z=f2bf(r2.y); cc.w=f2bf(r3.y); *(ushort4*)(Bp +  40) = cc;
      cc.x=f2bf(r0.z); cc.y=f2bf(r1.z); cc.z=f2bf(r2.z); cc.w=f2bf(r3.z); *(ushort4*)(Bp +  80) = cc;
      cc.x=f2bf(r0.w); cc.y=f2bf(r1.w); cc.z=f2bf(r2.w); cc.w=f2bf(r3.w); *(ushort4*)(Bp + 120) = cc;
    }
    __syncthreads();
    short8 af[4], bfv[4];
#pragma unroll
    for (int mi = 0; mi < 4; mi++)
      af[mi] = *(const short8*)(Al + (wrow + mi*16 + m16)*40 + quad*8);
#pragma unroll
    for (int ni = 0; ni < 4; ni++)
      bfv[ni] = *(const short8*)(Bl + (wcol + ni*16 + m16)*40 + quad*8);
    __syncthreads();
#pragma unroll
    for (int mi = 0; mi < 4; mi++)
#pragma unroll
      for (int ni = 0; ni < 4; ni++)
        acc[mi][ni] = __builtin_amdgcn_mfma_f32_16x16x32_bf16(af[mi], bfv[ni], acc[mi][ni], 0, 0, 0);
  }
  size_t Ybase = (size_t)(offs[g] + M0) * DD;
#pragma unroll
  for (int mi = 0; mi < 4; mi++)
#pragma unroll
    for (int ni = 0; ni < 4; ni++)
#pragma unroll
      for (int r = 0; r < 4; r++) {
        int row = wrow + mi*16 + quad*4 + r;
        if (M0 + row < count) {
          int col = n0 + wcol + ni*16 + m16;
          Y[Ybase + (size_t)row * DD + col] = acc[mi][ni][r];
        }
      }
}

// ---------------- per-slot LN_out stats ----------------
__global__ __launch_bounds__(256) void k_slotstats(
    const float* __restrict__ xf, const float* __restrict__ Y,
    const int* __restrict__ offs, const int* __restrict__ slot_token,
    float* __restrict__ sstats)
{
  int s = blockIdx.x;
  if (s >= offs[NG]) return;
  int t = slot_token[s];
  int d = threadIdx.x * 4;
  float4 yv = *(const float4*)(Y + (size_t)s*DD + d);
  float4 xv = *(const float4*)(xf + (size_t)t*DD + d);
  float z0 = xv.x + yv.x, z1 = xv.y + yv.y, z2 = xv.z + yv.z, z3 = xv.w + yv.w;
  float s1 = z0 + z1 + z2 + z3;
  float s2 = z0*z0 + z1*z1 + z2*z2 + z3*z3;
#pragma unroll
  for (int m = 32; m >= 1; m >>= 1) { s1 += __shfl_xor(s1, m); s2 += __shfl_xor(s2, m); }
  __shared__ float red[8];
  int wave = threadIdx.x >> 6, lane = threadIdx.x & 63;
  if (lane == 0) { red[wave*2] = s1; red[wave*2 + 1] = s2; }
  __syncthreads();
  if (threadIdx.x == 0) {
    float a = red[0] + red[2] + red[4] + red[6];
    float b = red[1] + red[3] + red[5] + red[7];
    float mean = a / DD;
    float var  = b / DD - mean * mean;
    sstats[s*2]   = mean;
    sstats[s*2+1] = rsqrtf(var + EPSV);
  }
}

// ---------------- final combine: LN_out, coef-sum, cluster LN, gate-sum ----------------
__global__ __launch_bounds__(256) void k_final(
    const float* __restrict__ xf, const float* __restrict__ Y,
    const float* __restrict__ sstats, const int* __restrict__ inv_slot,
    const float* __restrict__ gate, const float* __restrict__ coefs,
    const float* __restrict__ lout_g, const float* __restrict__ lout_b,
    const float* __restrict__ cln_g, const float* __restrict__ cln_b,
    float* __restrict__ out)
{
  int t = blockIdx.x;
  int d = threadIdx.x * 4;
  int wave = threadIdx.x >> 6, lane = threadIdx.x & 63;
  float4 xv = *(const float4*)(xf + (size_t)t*DD + d);
  float4 o = {0.f, 0.f, 0.f, 0.f};
  __shared__ float red[8];
  for (int c = 0; c < 4; c++) {
    float gt = gate[t*4 + c];
    if (gt == 0.f) continue;          // uniform across block
    float a0 = 0.f, a1 = 0.f, a2 = 0.f, a3 = 0.f;
    for (int e = 0; e < 4; e++) {
      float cf = coefs[t*16 + c*4 + e];
      if (cf <= 0.f) continue;        // uniform across block
      int g = c*4 + e;
      int s = inv_slot[t*16 + g];
      float4 yv = *(const float4*)(Y + (size_t)s*DD + d);
      float mean = sstats[s*2], rstd = sstats[s*2+1];
      float4 gg = *(const float4*)(lout_g + (size_t)g*DD + d);
      float4 bb = *(const float4*)(lout_b + (size_t)g*DD + d);
      a0 += cf * ((xv.x + yv.x - mean)*rstd*gg.x + bb.x);
      a1 += cf * ((xv.y + yv.y - mean)*rstd*gg.y + bb.y);
      a2 += cf * ((xv.z + yv.z - mean)*rstd*gg.z + bb.z);
      a3 += cf * ((xv.w + yv.w - mean)*rstd*gg.w + bb.w);
    }
    float s1 = a0 + a1 + a2 + a3;
    float s2 = a0*a0 + a1*a1 + a2*a2 + a3*a3;
#pragma unroll
    for (int m = 32; m >= 1; m >>= 1) { s1 += __shfl_xor(s1, m); s2 += __shfl_xor(s2, m); }
    if (lane == 0) { red[wave*2] = s1; red[wave*2 + 1] = s2; }
    __syncthreads();
    float ts1 = red[0] + red[2] + red[4] + red[6];
    float ts2 = red[1] + red[3] + red[5] + red[7];
    __syncthreads();
    float mean = ts1 / DD;
    float rstd = rsqrtf(ts2 / DD - mean*mean + EPSV);
    float4 cg = *(const float4*)(cln_g + (size_t)c*DD + d);
    float4 cb = *(const float4*)(cln_b + (size_t)c*DD + d);
    o.x += gt * ((a0 - mean)*rstd*cg.x + cb.x);
    o.y += gt * ((a1 - mean)*rstd*cg.y + cb.y);
    o.z += gt * ((a2 - mean)*rstd*cg.z + cb.z);
    o.w += gt * ((a3 - mean)*rstd*cg.w + cb.w);
  }
  *(float4*)(out + (size_t)t*DD + d) = o;
}

extern "C" void kernel_launch(void* const* d_in, const int* in_sizes, int n_in,
                              void* d_out, int out_size, void* d_ws, size_t ws_size,
                              hipStream_t stream) {
  (void)in_sizes; (void)n_in; (void)out_size; (void)ws_size;
  const float* x      = (const float*)d_in[0];
  const float* W1     = (const float*)d_in[1];
  const float* W2     = (const float*)d_in[2];
  const float* W3     = (const float*)d_in[3];
  const float* lin_g  = (const float*)d_in[4];
  const float* lin_b  = (const float*)d_in[5];
  const float* lout_g = (const float*)d_in[6];
  const float* lout_b = (const float*)d_in[7];
  const float* cln_g  = (const float*)d_in[8];
  const float* cln_b  = (const float*)d_in[9];
  const float* Wrc    = (const float*)d_in[10];
  const float* brc    = (const float*)d_in[11];
  const float* Wre    = (const float*)d_in[12];
  const float* bre    = (const float*)d_in[13];
  float* out = (float*)d_out;
  char* ws = (char*)d_ws;

  // workspace layout (bytes)
  int*   counts     = (int*)(ws + 0);          //    64
  int*   cursor     = (int*)(ws + 64);         //    64
  int*   offs       = (int*)(ws + 128);        //   128 (pad)
  float* gate       = (float*)(ws + 256);      // 32768
  float* coefs      = (float*)(ws + 33024);    // 131072
  float* tstats     = (float*)(ws + 164096);   // 16384
  int*   slot_token = (int*)(ws + 180480);     // 32768
  int*   inv_slot   = (int*)(ws + 213248);     // 131072
  float* sstats     = (float*)(ws + 344320);   // 65536
  unsigned short* Xg = (unsigned short*)(ws + 409856);              // 16 MiB
  unsigned short* H  = (unsigned short*)(ws + 409856 + 16777216);   // 32 MiB
  float* Y = (float*)(ws + 409856 + 16777216 + 33554432);           // 32 MiB
  // total ~80.4 MiB

  hipMemsetAsync(ws, 0, 256, stream);                 // counts + cursor + offs
  hipMemsetAsync(ws + 256, 0, 163840, stream);        // gate + coefs

  k_route<<<TT, 256, 0, stream>>>(x, Wrc, brc, Wre, bre, gate, coefs, tstats, counts);
  k_offsets<<<1, 64, 0, stream>>>(counts, offs);
  k_fill<<<(TT*NG)/256, 256, 0, stream>>>(coefs, offs, cursor, slot_token, inv_slot);
  k_gather<<<CAP, 256, 0, stream>>>(x, tstats, lin_g, lin_b, offs, slot_token, Xg);
  k_gemm1<true ><<<dim3(16, 16, 8), 256, 0, stream>>>(Xg, W1, W2, counts, offs, H);
  k_gemm1<false><<<dim3(16, 16, 8), 256, 0, stream>>>(Xg, W1, W2, counts, offs, H);
  k_gemm2<<<dim3(16, 8, 16), 256, 0, stream>>>(H, W3, counts, offs, Y);
  k_slotstats<<<CAP, 256, 0, stream>>>(x, Y, offs, slot_token, sstats);
  k_final<<<TT, 256, 0, stream>>>(x, Y, sstats, inv_slot, gate, coefs,
                                  lout_g, lout_b, cln_g, cln_b, out);
}

// Round 2
// 1208.254 us; speedup vs baseline: 1.1152x; 1.1152x over previous
//
#include <hip/hip_runtime.h>
#include <cstdint>
#include <cstddef>

#define TT 2048
#define DD 1024
#define FF 2048
#define NG 16
#define CAP (TT*4)
#define EPSV 1e-5f

typedef __attribute__((ext_vector_type(8))) short short8;
typedef __attribute__((ext_vector_type(4))) float floatx4;

__device__ inline unsigned short f2bf(float f) {
  union { float f; unsigned int u; } v; v.f = f;
  unsigned int r = v.u + 0x7fffu + ((v.u >> 16) & 1u);
  return (unsigned short)(r >> 16);
}

__device__ __forceinline__ void gl2lds(const void* g, void* l) {
  __builtin_amdgcn_global_load_lds(
      (const __attribute__((address_space(1))) void*)g,
      (__attribute__((address_space(3))) void*)l, 16, 0, 0);
}

// ---------------- routing ----------------
__global__ __launch_bounds__(256) void k_route(
    const float* __restrict__ xf, const float* __restrict__ Wrc,
    const float* __restrict__ brc, const float* __restrict__ Wre,
    const float* __restrict__ bre, float* __restrict__ gate,
    float* __restrict__ coefs, float* __restrict__ tstats,
    int* __restrict__ counts)
{
  int t = blockIdx.x;
  const float* xr = xf + (size_t)t * DD;
  float v[22];
#pragma unroll
  for (int i = 0; i < 22; i++) v[i] = 0.f;
  for (int d = threadIdx.x; d < DD; d += 256) {
    float x = xr[d];
    v[20] += x; v[21] += x * x;
    float4 wc = *(const float4*)(Wrc + (size_t)d * 4);
    v[0] += x * wc.x; v[1] += x * wc.y; v[2] += x * wc.z; v[3] += x * wc.w;
#pragma unroll
    for (int c = 0; c < 4; c++) {
      float4 we = *(const float4*)(Wre + ((size_t)c * DD + d) * 4);
      v[4 + c*4 + 0] += x * we.x; v[4 + c*4 + 1] += x * we.y;
      v[4 + c*4 + 2] += x * we.z; v[4 + c*4 + 3] += x * we.w;
    }
  }
#pragma unroll
  for (int m = 32; m >= 1; m >>= 1)
#pragma unroll
    for (int i = 0; i < 22; i++) v[i] += __shfl_xor(v[i], m);
  __shared__ float red[4][22];
  int wave = threadIdx.x >> 6, lane = threadIdx.x & 63;
  if (lane == 0) for (int i = 0; i < 22; i++) red[wave][i] = v[i];
  __syncthreads();
  if (threadIdx.x == 0) {
    for (int i = 0; i < 22; i++) v[i] = red[0][i] + red[1][i] + red[2][i] + red[3][i];
    float mean = v[20] / DD;
    float var  = v[21] / DD - mean * mean;
    tstats[t*2]   = mean;
    tstats[t*2+1] = rsqrtf(var + EPSV);
    float p[4]; float mx = -1e30f;
    for (int c = 0; c < 4; c++) { v[c] += brc[c]; mx = fmaxf(mx, v[c]); }
    for (int c = 0; c < 4; c++) p[c] = expf(v[c] - mx);
    int c0 = 0;
    for (int c = 1; c < 4; c++) if (p[c] > p[c0]) c0 = c;
    int c1 = (c0 == 0) ? 1 : 0;
    for (int c = 0; c < 4; c++) if (c != c0 && p[c] > p[c1]) c1 = c;
    float ws = p[c0] + p[c1];
    gate[t*4 + c0] = p[c0] / ws;
    gate[t*4 + c1] = p[c1] / ws;
    int sels[2] = {c0, c1};
    for (int si = 0; si < 2; si++) {
      int c = sels[si];
      float l[4];
      for (int e = 0; e < 4; e++) l[e] = v[4 + c*4 + e] + bre[c*4 + e];
      int e0 = 0;
      for (int e = 1; e < 4; e++) if (l[e] > l[e0]) e0 = e;
      int e1 = (e0 == 0) ? 1 : 0;
      for (int e = 0; e < 4; e++) if (e != e0 && l[e] > l[e1]) e1 = e;
      float q1 = expf(l[e1] - l[e0]);
      float r0 = 1.f / (1.f + q1);
      float r1 = q1 / (1.f + q1);
      if (r0 > 0.f) { coefs[t*16 + c*4 + e0] = r0; atomicAdd(&counts[c*4 + e0], 1); }
      if (r1 > 0.f) { coefs[t*16 + c*4 + e1] = r1; atomicAdd(&counts[c*4 + e1], 1); }
    }
  }
}

__global__ void k_offsets(const int* __restrict__ counts, int* __restrict__ offs) {
  if (threadIdx.x == 0 && blockIdx.x == 0) {
    int s = 0;
    for (int i = 0; i < NG; i++) { offs[i] = s; s += counts[i]; }
    offs[NG] = s;
  }
}

__global__ __launch_bounds__(256) void k_fill(
    const float* __restrict__ coefs, const int* __restrict__ offs,
    int* __restrict__ cursor, int* __restrict__ slot_token, int* __restrict__ inv_slot)
{
  int idx = blockIdx.x * 256 + threadIdx.x;
  if (idx >= TT * NG) return;
  int t = idx >> 4, ce = idx & 15;
  if (coefs[idx] > 0.f) {
    int pos = atomicAdd(&cursor[ce], 1);
    int s = offs[ce] + pos;
    slot_token[s] = t;
    inv_slot[idx] = s;
  }
}

// ---------------- weight transpose + fp32->bf16 ----------------
// src group [K][N] fp32 -> dst group [N][K] bf16
__global__ __launch_bounds__(256) void k_transpose(
    const float* __restrict__ src, unsigned short* __restrict__ dst,
    int K, int N, int swiglu_only)
{
  int g, gd;
  if (swiglu_only) { g = ((int)blockIdx.z >> 1) * 4 + ((blockIdx.z & 1) ? 3 : 0); gd = blockIdx.z; }
  else { g = blockIdx.z; gd = g; }
  const float* S = src + (size_t)g * K * N;
  unsigned short* D = dst + (size_t)gd * K * N;
  int kb = blockIdx.y * 64, nb = blockIdx.x * 64;
  __shared__ float T[64][65];
  int r0 = threadIdx.x >> 4;
  int c4 = (threadIdx.x & 15) * 4;
#pragma unroll
  for (int r = 0; r < 4; r++) {
    int row = r0 + 16 * r;
    float4 v = *(const float4*)(S + (size_t)(kb + row) * N + nb + c4);
    T[row][c4] = v.x; T[row][c4+1] = v.y; T[row][c4+2] = v.z; T[row][c4+3] = v.w;
  }
  __syncthreads();
#pragma unroll
  for (int r = 0; r < 4; r++) {
    int nrow = r0 + 16 * r;
    ushort4 o;
    o.x = f2bf(T[c4+0][nrow]); o.y = f2bf(T[c4+1][nrow]);
    o.z = f2bf(T[c4+2][nrow]); o.w = f2bf(T[c4+3][nrow]);
    *(ushort4*)(D + (size_t)(nb + nrow) * K + kb + c4) = o;
  }
}

// ---------------- gather + LN_in -> bf16 ----------------
__global__ __launch_bounds__(256) void k_gather(
    const float* __restrict__ xf, const float* __restrict__ tstats,
    const float* __restrict__ lin_g, const float* __restrict__ lin_b,
    const int* __restrict__ offs, const int* __restrict__ slot_token,
    unsigned short* __restrict__ Xg)
{
  int s = blockIdx.x;
  if (s >= offs[NG]) return;
  int g = 0;
  while (g < NG - 1 && s >= offs[g + 1]) g++;
  int t = slot_token[s];
  float mean = tstats[t*2], rstd = tstats[t*2+1];
  int d = threadIdx.x * 4;
  float4 x  = *(const float4*)(xf + (size_t)t*DD + d);
  float4 gg = *(const float4*)(lin_g + (size_t)g*DD + d);
  float4 bb = *(const float4*)(lin_b + (size_t)g*DD + d);
  ushort4 o;
  o.x = f2bf((x.x - mean)*rstd*gg.x + bb.x);
  o.y = f2bf((x.y - mean)*rstd*gg.y + bb.y);
  o.z = f2bf((x.z - mean)*rstd*gg.z + bb.z);
  o.w = f2bf((x.w - mean)*rstd*gg.w + bb.w);
  *(ushort4*)(Xg + (size_t)s*DD + d) = o;
}

// ---------------- GEMM1: Xg @ W1t^T (+W2t^T) -> act -> H (bf16) ----------------
// A: [count][DD] bf16 rows; B: W1t group [FF][DD] bf16 rows (n-major, k-contig)
template<bool DUAL>
__global__ __launch_bounds__(256) void k_gemm1(
    const unsigned short* __restrict__ Xg, const unsigned short* __restrict__ W1t,
    const unsigned short* __restrict__ W2t, const int* __restrict__ counts,
    const int* __restrict__ offs, unsigned short* __restrict__ H)
{
  int z = blockIdx.z;
  int c = z >> 1;
  int e = DUAL ? ((z & 1) ? 3 : 0) : ((z & 1) + 1);
  int g = c * 4 + e;
  int count = counts[g];
  int M0 = blockIdx.x * 128;
  if (M0 >= count) return;
  int n0 = blockIdx.y * 128;
  __shared__ unsigned short Al[128 * 32];
  __shared__ unsigned short B0[128 * 32];
  __shared__ unsigned short B1[DUAL ? 128 * 32 : 16];
  const char* Abase  = (const char*)(Xg + (size_t)(offs[g] + M0) * DD);
  const char* B0base = (const char*)(W1t + (size_t)g * DD * FF + (size_t)n0 * DD);
  const char* B1base = (const char*)(W2t + (size_t)z * DD * FF + (size_t)n0 * DD);
  floatx4 zero4 = {0.f, 0.f, 0.f, 0.f};
  floatx4 acc[4][4], acc2[DUAL ? 4 : 1][4];
#pragma unroll
  for (int i = 0; i < 4; i++)
#pragma unroll
    for (int j = 0; j < 4; j++) { acc[i][j] = zero4; if constexpr (DUAL) acc2[i][j] = zero4; }
  int tid = threadIdx.x, lane = tid & 63, wv = tid >> 6;
  int m16 = lane & 15, quad = lane >> 4;
  int wrow = (wv >> 1) * 64, wcol = (wv & 1) * 64;
  // staging: two 1KB wave-chunks per tile; row stride 2048 B, 64 B per row
  int lin0 = ((wv * 2 + 0) * 64 + lane) * 16;
  int lin1 = ((wv * 2 + 1) * 64 + lane) * 16;
  size_t aoff0 = (size_t)(lin0 >> 6) * 2048 + (lin0 & 63);
  size_t aoff1 = (size_t)(lin1 >> 6) * 2048 + (lin1 & 63);
  unsigned short* ldsA0 = Al + (wv * 2 + 0) * 512;
  unsigned short* ldsA1 = Al + (wv * 2 + 1) * 512;
  unsigned short* ldsB00 = B0 + (wv * 2 + 0) * 512;
  unsigned short* ldsB01 = B0 + (wv * 2 + 1) * 512;
  unsigned short* ldsB10 = B1 + (wv * 2 + 0) * 512;
  unsigned short* ldsB11 = B1 + (wv * 2 + 1) * 512;
  for (int kb = 0; kb < DD * 2; kb += 64) {
    gl2lds(Abase + aoff0 + kb, ldsA0);
    gl2lds(Abase + aoff1 + kb, ldsA1);
    gl2lds(B0base + aoff0 + kb, ldsB00);
    gl2lds(B0base + aoff1 + kb, ldsB01);
    if constexpr (DUAL) {
      gl2lds(B1base + aoff0 + kb, ldsB10);
      gl2lds(B1base + aoff1 + kb, ldsB11);
    }
    __syncthreads();
    short8 af[4], b0v[4], b1v[4];
#pragma unroll
    for (int mi = 0; mi < 4; mi++)
      af[mi] = *(const short8*)(Al + (wrow + mi*16 + m16) * 32 + quad * 8);
#pragma unroll
    for (int ni = 0; ni < 4; ni++) {
      b0v[ni] = *(const short8*)(B0 + (wcol + ni*16 + m16) * 32 + quad * 8);
      if constexpr (DUAL) b1v[ni] = *(const short8*)(B1 + (wcol + ni*16 + m16) * 32 + quad * 8);
    }
    __syncthreads();
#pragma unroll
    for (int mi = 0; mi < 4; mi++)
#pragma unroll
      for (int ni = 0; ni < 4; ni++) {
        acc[mi][ni] = __builtin_amdgcn_mfma_f32_16x16x32_bf16(af[mi], b0v[ni], acc[mi][ni], 0, 0, 0);
        if constexpr (DUAL)
          acc2[mi][ni] = __builtin_amdgcn_mfma_f32_16x16x32_bf16(af[mi], b1v[ni], acc2[mi][ni], 0, 0, 0);
      }
  }
  size_t Hbase = (size_t)(offs[g] + M0) * FF;
#pragma unroll
  for (int mi = 0; mi < 4; mi++)
#pragma unroll
    for (int ni = 0; ni < 4; ni++)
#pragma unroll
      for (int r = 0; r < 4; r++) {
        int row = wrow + mi*16 + quad*4 + r;
        if (M0 + row < count) {
          int col = n0 + wcol + ni*16 + m16;
          float h1 = acc[mi][ni][r];
          float h;
          if constexpr (DUAL) {
            float h2 = acc2[mi][ni][r];
            float sil = h2 / (1.f + expf(-h2));
            h = sil * h2 * h1;
          } else {
            if (e == 1) h = 0.5f * h1 * (1.f + erff(h1 * 0.70710678118f));
            else        h = fmaxf(h1, 0.f);
          }
          H[Hbase + (size_t)row * FF + col] = f2bf(h);
        }
      }
}

// ---------------- GEMM2: H @ W3t^T -> Y (fp32) ----------------
// A: H [count][FF] bf16; B: W3t group [DD][FF] bf16
__global__ __launch_bounds__(256) void k_gemm2(
    const unsigned short* __restrict__ H, const unsigned short* __restrict__ W3t,
    const int* __restrict__ counts, const int* __restrict__ offs,
    float* __restrict__ Y)
{
  int g = blockIdx.z;
  int count = counts[g];
  int M0 = blockIdx.x * 128;
  if (M0 >= count) return;
  int n0 = blockIdx.y * 128;
  __shared__ unsigned short Al[128 * 32];
  __shared__ unsigned short Bl[128 * 32];
  const char* Abase = (const char*)(H + (size_t)(offs[g] + M0) * FF);
  const char* Bbase = (const char*)(W3t + (size_t)g * DD * FF + (size_t)n0 * FF);
  floatx4 zero4 = {0.f, 0.f, 0.f, 0.f};
  floatx4 acc[4][4];
#pragma unroll
  for (int i = 0; i < 4; i++)
#pragma unroll
    for (int j = 0; j < 4; j++) acc[i][j] = zero4;
  int tid = threadIdx.x, lane = tid & 63, wv = tid >> 6;
  int m16 = lane & 15, quad = lane >> 4;
  int wrow = (wv >> 1) * 64, wcol = (wv & 1) * 64;
  int lin0 = ((wv * 2 + 0) * 64 + lane) * 16;
  int lin1 = ((wv * 2 + 1) * 64 + lane) * 16;
  size_t aoff0 = (size_t)(lin0 >> 6) * 4096 + (lin0 & 63);
  size_t aoff1 = (size_t)(lin1 >> 6) * 4096 + (lin1 & 63);
  unsigned short* ldsA0 = Al + (wv * 2 + 0) * 512;
  unsigned short* ldsA1 = Al + (wv * 2 + 1) * 512;
  unsigned short* ldsB0 = Bl + (wv * 2 + 0) * 512;
  unsigned short* ldsB1 = Bl + (wv * 2 + 1) * 512;
  for (int kb = 0; kb < FF * 2; kb += 64) {
    gl2lds(Abase + aoff0 + kb, ldsA0);
    gl2lds(Abase + aoff1 + kb, ldsA1);
    gl2lds(Bbase + aoff0 + kb, ldsB0);
    gl2lds(Bbase + aoff1 + kb, ldsB1);
    __syncthreads();
    short8 af[4], bv[4];
#pragma unroll
    for (int mi = 0; mi < 4; mi++)
      af[mi] = *(const short8*)(Al + (wrow + mi*16 + m16) * 32 + quad * 8);
#pragma unroll
    for (int ni = 0; ni < 4; ni++)
      bv[ni] = *(const short8*)(Bl + (wcol + ni*16 + m16) * 32 + quad * 8);
    __syncthreads();
#pragma unroll
    for (int mi = 0; mi < 4; mi++)
#pragma unroll
      for (int ni = 0; ni < 4; ni++)
        acc[mi][ni] = __builtin_amdgcn_mfma_f32_16x16x32_bf16(af[mi], bv[ni], acc[mi][ni], 0, 0, 0);
  }
  size_t Ybase = (size_t)(offs[g] + M0) * DD;
#pragma unroll
  for (int mi = 0; mi < 4; mi++)
#pragma unroll
    for (int ni = 0; ni < 4; ni++)
#pragma unroll
      for (int r = 0; r < 4; r++) {
        int row = wrow + mi*16 + quad*4 + r;
        if (M0 + row < count) {
          int col = n0 + wcol + ni*16 + m16;
          Y[Ybase + (size_t)row * DD + col] = acc[mi][ni][r];
        }
      }
}

// ---------------- per-slot LN_out stats ----------------
__global__ __launch_bounds__(256) void k_slotstats(
    const float* __restrict__ xf, const float* __restrict__ Y,
    const int* __restrict__ offs, const int* __restrict__ slot_token,
    float* __restrict__ sstats)
{
  int s = blockIdx.x;
  if (s >= offs[NG]) return;
  int t = slot_token[s];
  int d = threadIdx.x * 4;
  float4 yv = *(const float4*)(Y + (size_t)s*DD + d);
  float4 xv = *(const float4*)(xf + (size_t)t*DD + d);
  float z0 = xv.x + yv.x, z1 = xv.y + yv.y, z2 = xv.z + yv.z, z3 = xv.w + yv.w;
  float s1 = z0 + z1 + z2 + z3;
  float s2 = z0*z0 + z1*z1 + z2*z2 + z3*z3;
#pragma unroll
  for (int m = 32; m >= 1; m >>= 1) { s1 += __shfl_xor(s1, m); s2 += __shfl_xor(s2, m); }
  __shared__ float red[8];
  int wave = threadIdx.x >> 6, lane = threadIdx.x & 63;
  if (lane == 0) { red[wave*2] = s1; red[wave*2 + 1] = s2; }
  __syncthreads();
  if (threadIdx.x == 0) {
    float a = red[0] + red[2] + red[4] + red[6];
    float b = red[1] + red[3] + red[5] + red[7];
    float mean = a / DD;
    float var  = b / DD - mean * mean;
    sstats[s*2]   = mean;
    sstats[s*2+1] = rsqrtf(var + EPSV);
  }
}

// ---------------- final combine ----------------
__global__ __launch_bounds__(256) void k_final(
    const float* __restrict__ xf, const float* __restrict__ Y,
    const float* __restrict__ sstats, const int* __restrict__ inv_slot,
    const float* __restrict__ gate, const float* __restrict__ coefs,
    const float* __restrict__ lout_g, const float* __restrict__ lout_b,
    const float* __restrict__ cln_g, const float* __restrict__ cln_b,
    float* __restrict__ out)
{
  int t = blockIdx.x;
  int d = threadIdx.x * 4;
  int wave = threadIdx.x >> 6, lane = threadIdx.x & 63;
  float4 xv = *(const float4*)(xf + (size_t)t*DD + d);
  float4 o = {0.f, 0.f, 0.f, 0.f};
  __shared__ float red[8];
  for (int c = 0; c < 4; c++) {
    float gt = gate[t*4 + c];
    if (gt == 0.f) continue;
    float a0 = 0.f, a1 = 0.f, a2 = 0.f, a3 = 0.f;
    for (int e = 0; e < 4; e++) {
      float cf = coefs[t*16 + c*4 + e];
      if (cf <= 0.f) continue;
      int g = c*4 + e;
      int s = inv_slot[t*16 + g];
      float4 yv = *(const float4*)(Y + (size_t)s*DD + d);
      float mean = sstats[s*2], rstd = sstats[s*2+1];
      float4 gg = *(const float4*)(lout_g + (size_t)g*DD + d);
      float4 bb = *(const float4*)(lout_b + (size_t)g*DD + d);
      a0 += cf * ((xv.x + yv.x - mean)*rstd*gg.x + bb.x);
      a1 += cf * ((xv.y + yv.y - mean)*rstd*gg.y + bb.y);
      a2 += cf * ((xv.z + yv.z - mean)*rstd*gg.z + bb.z);
      a3 += cf * ((xv.w + yv.w - mean)*rstd*gg.w + bb.w);
    }
    float s1 = a0 + a1 + a2 + a3;
    float s2 = a0*a0 + a1*a1 + a2*a2 + a3*a3;
#pragma unroll
    for (int m = 32; m >= 1; m >>= 1) { s1 += __shfl_xor(s1, m); s2 += __shfl_xor(s2, m); }
    if (lane == 0) { red[wave*2] = s1; red[wave*2 + 1] = s2; }
    __syncthreads();
    float ts1 = red[0] + red[2] + red[4] + red[6];
    float ts2 = red[1] + red[3] + red[5] + red[7];
    __syncthreads();
    float mean = ts1 / DD;
    float rstd = rsqrtf(ts2 / DD - mean*mean + EPSV);
    float4 cg = *(const float4*)(cln_g + (size_t)c*DD + d);
    float4 cb = *(const float4*)(cln_b + (size_t)c*DD + d);
    o.x += gt * ((a0 - mean)*rstd*cg.x + cb.x);
    o.y += gt * ((a1 - mean)*rstd*cg.y + cb.y);
    o.z += gt * ((a2 - mean)*rstd*cg.z + cb.z);
    o.w += gt * ((a3 - mean)*rstd*cg.w + cb.w);
  }
  *(float4*)(out + (size_t)t*DD + d) = o;
}

extern "C" void kernel_launch(void* const* d_in, const int* in_sizes, int n_in,
                              void* d_out, int out_size, void* d_ws, size_t ws_size,
                              hipStream_t stream) {
  (void)in_sizes; (void)n_in; (void)out_size; (void)ws_size;
  const float* x      = (const float*)d_in[0];
  const float* W1     = (const float*)d_in[1];
  const float* W2     = (const float*)d_in[2];
  const float* W3     = (const float*)d_in[3];
  const float* lin_g  = (const float*)d_in[4];
  const float* lin_b  = (const float*)d_in[5];
  const float* lout_g = (const float*)d_in[6];
  const float* lout_b = (const float*)d_in[7];
  const float* cln_g  = (const float*)d_in[8];
  const float* cln_b  = (const float*)d_in[9];
  const float* Wrc    = (const float*)d_in[10];
  const float* brc    = (const float*)d_in[11];
  const float* Wre    = (const float*)d_in[12];
  const float* bre    = (const float*)d_in[13];
  float* out = (float*)d_out;
  char* ws = (char*)d_ws;

  // workspace layout (bytes)
  int*   counts     = (int*)(ws + 0);
  int*   cursor     = (int*)(ws + 64);
  int*   offs       = (int*)(ws + 128);
  float* gate       = (float*)(ws + 256);
  float* coefs      = (float*)(ws + 33024);
  float* tstats     = (float*)(ws + 164096);
  int*   slot_token = (int*)(ws + 180480);
  int*   inv_slot   = (int*)(ws + 213248);
  float* sstats     = (float*)(ws + 344320);
  unsigned short* Xg  = (unsigned short*)(ws + 1048576);     // 16 MiB
  unsigned short* H   = (unsigned short*)(ws + 17825792);    // 32 MiB
  unsigned short* W1t = (unsigned short*)(ws + 51380224);    // 64 MiB (16 groups [FF][DD])
  float*          Y   = (float*)(ws + 51380224);             // aliases W1t (dead after gemm1)
  unsigned short* W2t = (unsigned short*)(ws + 118489088);   // 32 MiB (8 swiglu groups [FF][DD])
  unsigned short* W3t = (unsigned short*)(ws + 152043520);   // 64 MiB (16 groups [DD][FF])
  // total ~209 MiB

  hipMemsetAsync(ws, 0, 256, stream);
  hipMemsetAsync(ws + 256, 0, 163840, stream);

  k_transpose<<<dim3(FF/64, DD/64, 16), 256, 0, stream>>>(W1, W1t, DD, FF, 0);
  k_transpose<<<dim3(FF/64, DD/64,  8), 256, 0, stream>>>(W2, W2t, DD, FF, 1);
  k_transpose<<<dim3(DD/64, FF/64, 16), 256, 0, stream>>>(W3, W3t, FF, DD, 0);

  k_route<<<TT, 256, 0, stream>>>(x, Wrc, brc, Wre, bre, gate, coefs, tstats, counts);
  k_offsets<<<1, 64, 0, stream>>>(counts, offs);
  k_fill<<<(TT*NG)/256, 256, 0, stream>>>(coefs, offs, cursor, slot_token, inv_slot);
  k_gather<<<CAP, 256, 0, stream>>>(x, tstats, lin_g, lin_b, offs, slot_token, Xg);
  k_gemm1<true ><<<dim3(16, 16, 8), 256, 0, stream>>>(Xg, W1t, W2t, counts, offs, H);
  k_gemm1<false><<<dim3(16, 16, 8), 256, 0, stream>>>(Xg, W1t, W2t, counts, offs, H);
  k_gemm2<<<dim3(16, 8, 16), 256, 0, stream>>>(H, W3t, counts, offs, Y);
  k_slotstats<<<CAP, 256, 0, stream>>>(x, Y, offs, slot_token, sstats);
  k_final<<<TT, 256, 0, stream>>>(x, Y, sstats, inv_slot, gate, coefs,
                                  lout_g, lout_b, cln_g, cln_b, out);
}

// Round 3
// 808.806 us; speedup vs baseline: 1.6659x; 1.4939x over previous
//
#include <hip/hip_runtime.h>
#include <cstdint>
#include <cstddef>

#define TT 2048
#define DD 1024
#define FF 2048
#define NG 16
#define PSLOT 10240
#define EPSV 1e-5f

typedef __attribute__((ext_vector_type(8))) short short8;
typedef __attribute__((ext_vector_type(4))) float floatx4;

__device__ inline unsigned short f2bf(float f) {
  union { float f; unsigned int u; } v; v.f = f;
  unsigned int r = v.u + 0x7fffu + ((v.u >> 16) & 1u);
  return (unsigned short)(r >> 16);
}

__device__ __forceinline__ void gl2lds(const void* g, void* l) {
  __builtin_amdgcn_global_load_lds(
      (const __attribute__((address_space(1))) void*)g,
      (__attribute__((address_space(3))) void*)l, 16, 0, 0);
}

// ---------------- routing ----------------
__global__ __launch_bounds__(256) void k_route(
    const float* __restrict__ xf, const float* __restrict__ Wrc,
    const float* __restrict__ brc, const float* __restrict__ Wre,
    const float* __restrict__ bre, float* __restrict__ gate,
    float* __restrict__ coefs, float* __restrict__ tstats,
    int* __restrict__ counts)
{
  int t = blockIdx.x;
  const float* xr = xf + (size_t)t * DD;
  float v[22];
#pragma unroll
  for (int i = 0; i < 22; i++) v[i] = 0.f;
  for (int d = threadIdx.x; d < DD; d += 256) {
    float x = xr[d];
    v[20] += x; v[21] += x * x;
    float4 wc = *(const float4*)(Wrc + (size_t)d * 4);
    v[0] += x * wc.x; v[1] += x * wc.y; v[2] += x * wc.z; v[3] += x * wc.w;
#pragma unroll
    for (int c = 0; c < 4; c++) {
      float4 we = *(const float4*)(Wre + ((size_t)c * DD + d) * 4);
      v[4 + c*4 + 0] += x * we.x; v[4 + c*4 + 1] += x * we.y;
      v[4 + c*4 + 2] += x * we.z; v[4 + c*4 + 3] += x * we.w;
    }
  }
#pragma unroll
  for (int m = 32; m >= 1; m >>= 1)
#pragma unroll
    for (int i = 0; i < 22; i++) v[i] += __shfl_xor(v[i], m);
  __shared__ float red[4][22];
  int wave = threadIdx.x >> 6, lane = threadIdx.x & 63;
  if (lane == 0) for (int i = 0; i < 22; i++) red[wave][i] = v[i];
  __syncthreads();
  if (threadIdx.x == 0) {
    for (int i = 0; i < 22; i++) v[i] = red[0][i] + red[1][i] + red[2][i] + red[3][i];
    float mean = v[20] / DD;
    float var  = v[21] / DD - mean * mean;
    tstats[t*2]   = mean;
    tstats[t*2+1] = rsqrtf(var + EPSV);
    float p[4]; float mx = -1e30f;
    for (int c = 0; c < 4; c++) { v[c] += brc[c]; mx = fmaxf(mx, v[c]); }
    for (int c = 0; c < 4; c++) p[c] = expf(v[c] - mx);
    int c0 = 0;
    for (int c = 1; c < 4; c++) if (p[c] > p[c0]) c0 = c;
    int c1 = (c0 == 0) ? 1 : 0;
    for (int c = 0; c < 4; c++) if (c != c0 && p[c] > p[c1]) c1 = c;
    float ws = p[c0] + p[c1];
    gate[t*4 + c0] = p[c0] / ws;
    gate[t*4 + c1] = p[c1] / ws;
    int sels[2] = {c0, c1};
    for (int si = 0; si < 2; si++) {
      int c = sels[si];
      float l[4];
      for (int e = 0; e < 4; e++) l[e] = v[4 + c*4 + e] + bre[c*4 + e];
      int e0 = 0;
      for (int e = 1; e < 4; e++) if (l[e] > l[e0]) e0 = e;
      int e1 = (e0 == 0) ? 1 : 0;
      for (int e = 0; e < 4; e++) if (e != e0 && l[e] > l[e1]) e1 = e;
      float q1 = expf(l[e1] - l[e0]);
      float r0 = 1.f / (1.f + q1);
      float r1 = q1 / (1.f + q1);
      if (r0 > 0.f) { coefs[t*16 + c*4 + e0] = r0; atomicAdd(&counts[c*4 + e0], 1); }
      if (r1 > 0.f) { coefs[t*16 + c*4 + e1] = r1; atomicAdd(&counts[c*4 + e1], 1); }
    }
  }
}

// padded (128-aligned) group offsets
__global__ void k_offsets(const int* __restrict__ counts, int* __restrict__ poffs) {
  if (threadIdx.x == 0 && blockIdx.x == 0) {
    int s = 0;
    for (int i = 0; i < NG; i++) { poffs[i] = s; s += (counts[i] + 127) & ~127; }
    poffs[NG] = s;
  }
}

__global__ __launch_bounds__(256) void k_fill(
    const float* __restrict__ coefs, const int* __restrict__ poffs,
    int* __restrict__ cursor, int* __restrict__ slot_token, int* __restrict__ inv_slot)
{
  int idx = blockIdx.x * 256 + threadIdx.x;
  if (idx >= TT * NG) return;
  int t = idx >> 4, ce = idx & 15;
  if (coefs[idx] > 0.f) {
    int pos = atomicAdd(&cursor[ce], 1);
    int s = poffs[ce] + pos;
    slot_token[s] = t;
    inv_slot[idx] = s;
  }
}

// ---------------- weight pack: [K][N] fp32 -> [K/64][N][64] bf16 ----------------
__global__ __launch_bounds__(256) void k_pack(
    const float* __restrict__ src, unsigned short* __restrict__ dst,
    int K, int N, int swiglu)
{
  int gd = blockIdx.z;
  int gs = swiglu ? ((gd >> 1) * 4 + ((gd & 1) ? 3 : 0)) : gd;
  const float* S = src + (size_t)gs * K * N;
  unsigned short* D = dst + (size_t)gd * K * N;
  int k0 = blockIdx.y * 64, nb = blockIdx.x * 64;
  __shared__ float T[64][65];
  int r0 = threadIdx.x >> 4, c4 = (threadIdx.x & 15) * 4;
#pragma unroll
  for (int r = 0; r < 4; r++) {
    int row = r0 + 16 * r;
    float4 v = *(const float4*)(S + (size_t)(k0 + row) * N + nb + c4);
    T[row][c4] = v.x; T[row][c4+1] = v.y; T[row][c4+2] = v.z; T[row][c4+3] = v.w;
  }
  __syncthreads();
  unsigned short* Dp = D + (size_t)(k0 >> 6) * ((size_t)N * 64);
#pragma unroll
  for (int r = 0; r < 4; r++) {
    int nrow = r0 + 16 * r;
    ushort4 o;
    o.x = f2bf(T[c4+0][nrow]); o.y = f2bf(T[c4+1][nrow]);
    o.z = f2bf(T[c4+2][nrow]); o.w = f2bf(T[c4+3][nrow]);
    *(ushort4*)(Dp + (size_t)(nb + nrow) * 64 + c4) = o;
  }
}

// ---------------- gather + LN_in -> packed bf16 [16][PSLOT][64] ----------------
__global__ __launch_bounds__(256) void k_gather(
    const float* __restrict__ xf, const float* __restrict__ tstats,
    const float* __restrict__ lin_g, const float* __restrict__ lin_b,
    const int* __restrict__ poffs, const int* __restrict__ counts,
    const int* __restrict__ slot_token, unsigned short* __restrict__ Xgp)
{
  int s = blockIdx.x;
  int g = 0;
  while (g < NG - 1 && s >= poffs[g + 1]) g++;
  if (s - poffs[g] >= counts[g]) return;
  int t = slot_token[s];
  float mean = tstats[t*2], rstd = tstats[t*2+1];
  int d = threadIdx.x * 4;
  float4 x  = *(const float4*)(xf + (size_t)t*DD + d);
  float4 gg = *(const float4*)(lin_g + (size_t)g*DD + d);
  float4 bb = *(const float4*)(lin_b + (size_t)g*DD + d);
  ushort4 o;
  o.x = f2bf((x.x - mean)*rstd*gg.x + bb.x);
  o.y = f2bf((x.y - mean)*rstd*gg.y + bb.y);
  o.z = f2bf((x.z - mean)*rstd*gg.z + bb.z);
  o.w = f2bf((x.w - mean)*rstd*gg.w + bb.w);
  *(ushort4*)(Xgp + (size_t)(d >> 6) * (PSLOT * 64) + (size_t)s * 64 + (d & 63)) = o;
}

// ---------------- GEMM1: Xgp @ W1p (+W2p) -> act -> Hp packed ----------------
template<bool DUAL>
__global__ __launch_bounds__(256) void k_gemm1(
    const unsigned short* __restrict__ Xgp, const unsigned short* __restrict__ W1p,
    const unsigned short* __restrict__ W2p, const int* __restrict__ counts,
    const int* __restrict__ poffs, unsigned short* __restrict__ Hp)
{
  int z = blockIdx.z;
  int g = DUAL ? ((z >> 1) * 4 + ((z & 1) ? 3 : 0)) : ((z >> 1) * 4 + 1 + (z & 1));
  int e = g & 3;
  int count = counts[g];
  int m = (blockIdx.x & 3) + 4 * blockIdx.y;
  int M0 = m * 128;
  if (M0 >= count) return;
  int n0 = (blockIdx.x >> 2) * 128;
  int slot0 = poffs[g] + M0;
  __shared__ unsigned short Al[128 * 64];
  __shared__ unsigned short B0[128 * 64];
  __shared__ unsigned short B1[DUAL ? 128 * 64 : 8];
  const char* Ab  = (const char*)Xgp + (size_t)slot0 * 128;
  const char* B0b = (const char*)(W1p + (size_t)g * DD * FF) + (size_t)n0 * 128;
  int w2o = (g >> 2) * 2 + (e == 3 ? 1 : 0);
  const char* B1b = (const char*)(W2p + (size_t)w2o * DD * FF) + (size_t)n0 * 128;
  floatx4 zero4 = {0.f, 0.f, 0.f, 0.f};
  floatx4 acc[4][4], acc2[DUAL ? 4 : 1][DUAL ? 4 : 1];
#pragma unroll
  for (int i = 0; i < 4; i++)
#pragma unroll
    for (int j = 0; j < 4; j++) { acc[i][j] = zero4; if constexpr (DUAL) acc2[i][j] = zero4; }
  int tid = threadIdx.x, lane = tid & 63, wv = tid >> 6;
  int m16 = lane & 15, quad = lane >> 4;
  int wrow = (wv >> 1) * 64, wcol = (wv & 1) * 64;
  int jp = lane & 7, r8 = lane >> 3;
  char* ldsA  = (char*)Al + wv * 4096;
  char* ldsB0 = (char*)B0 + wv * 4096;
  char* ldsB1 = (char*)B1 + wv * 4096;
  int goff[4];
#pragma unroll
  for (int q = 0; q < 4; q++) {
    int r = wv * 32 + q * 8 + r8;
    goff[q] = r * 128 + ((jp ^ (r & 7)) << 4);
  }
  int ph = m16 & 7;
  for (int kb = 0; kb < DD / 64; kb++) {
    const char* Ak  = Ab  + (size_t)kb * (PSLOT * 128);
    const char* B0k = B0b + (size_t)kb * (FF * 128);
    const char* B1k = B1b + (size_t)kb * (FF * 128);
#pragma unroll
    for (int q = 0; q < 4; q++) {
      gl2lds(Ak + goff[q],  ldsA  + q * 1024);
      gl2lds(B0k + goff[q], ldsB0 + q * 1024);
      if constexpr (DUAL) gl2lds(B1k + goff[q], ldsB1 + q * 1024);
    }
    __syncthreads();
#pragma unroll
    for (int ks = 0; ks < 2; ks++) {
      int co = ((quad + ks * 4) ^ ph) << 4;
      short8 af[4], b0v[4], b1v[4];
#pragma unroll
      for (int mi = 0; mi < 4; mi++)
        af[mi] = *(const short8*)((const char*)Al + (wrow + mi*16 + m16) * 128 + co);
#pragma unroll
      for (int ni = 0; ni < 4; ni++) {
        b0v[ni] = *(const short8*)((const char*)B0 + (wcol + ni*16 + m16) * 128 + co);
        if constexpr (DUAL)
          b1v[ni] = *(const short8*)((const char*)B1 + (wcol + ni*16 + m16) * 128 + co);
      }
#pragma unroll
      for (int mi = 0; mi < 4; mi++)
#pragma unroll
        for (int ni = 0; ni < 4; ni++) {
          acc[mi][ni] = __builtin_amdgcn_mfma_f32_16x16x32_bf16(af[mi], b0v[ni], acc[mi][ni], 0, 0, 0);
          if constexpr (DUAL)
            acc2[mi][ni] = __builtin_amdgcn_mfma_f32_16x16x32_bf16(af[mi], b1v[ni], acc2[mi][ni], 0, 0, 0);
        }
    }
    __syncthreads();
  }
#pragma unroll
  for (int mi = 0; mi < 4; mi++)
#pragma unroll
    for (int ni = 0; ni < 4; ni++)
#pragma unroll
      for (int r = 0; r < 4; r++) {
        int rl = wrow + mi*16 + quad*4 + r;
        if (M0 + rl < count) {
          int col = n0 + wcol + ni*16 + m16;
          float h1 = acc[mi][ni][r];
          float h;
          if constexpr (DUAL) {
            float h2 = acc2[mi][ni][r];
            float sil = h2 / (1.f + expf(-h2));
            h = sil * h2 * h1;
          } else {
            if (e == 1) h = 0.5f * h1 * (1.f + erff(h1 * 0.70710678118f));
            else        h = fmaxf(h1, 0.f);
          }
          Hp[(size_t)(col >> 6) * (PSLOT * 64) + (size_t)(slot0 + rl) * 64 + (col & 63)] = f2bf(h);
        }
      }
}

// ---------------- GEMM2: Hp @ W3p -> Y (fp32, natural rows) ----------------
__global__ __launch_bounds__(256) void k_gemm2(
    const unsigned short* __restrict__ Hp, const unsigned short* __restrict__ W3p,
    const int* __restrict__ counts, const int* __restrict__ poffs,
    float* __restrict__ Y)
{
  int g = blockIdx.z;
  int count = counts[g];
  int m = (blockIdx.x & 3) + 4 * blockIdx.y;
  int M0 = m * 128;
  if (M0 >= count) return;
  int n0 = (blockIdx.x >> 2) * 128;
  int slot0 = poffs[g] + M0;
  __shared__ unsigned short Al[128 * 64];
  __shared__ unsigned short Bl[128 * 64];
  const char* Ab = (const char*)Hp + (size_t)slot0 * 128;
  const char* Bb = (const char*)(W3p + (size_t)g * FF * DD) + (size_t)n0 * 128;
  floatx4 zero4 = {0.f, 0.f, 0.f, 0.f};
  floatx4 acc[4][4];
#pragma unroll
  for (int i = 0; i < 4; i++)
#pragma unroll
    for (int j = 0; j < 4; j++) acc[i][j] = zero4;
  int tid = threadIdx.x, lane = tid & 63, wv = tid >> 6;
  int m16 = lane & 15, quad = lane >> 4;
  int wrow = (wv >> 1) * 64, wcol = (wv & 1) * 64;
  int jp = lane & 7, r8 = lane >> 3;
  char* ldsA = (char*)Al + wv * 4096;
  char* ldsB = (char*)Bl + wv * 4096;
  int goff[4];
#pragma unroll
  for (int q = 0; q < 4; q++) {
    int r = wv * 32 + q * 8 + r8;
    goff[q] = r * 128 + ((jp ^ (r & 7)) << 4);
  }
  int ph = m16 & 7;
  for (int kb = 0; kb < FF / 64; kb++) {
    const char* Ak = Ab + (size_t)kb * (PSLOT * 128);
    const char* Bk = Bb + (size_t)kb * (DD * 128);
#pragma unroll
    for (int q = 0; q < 4; q++) {
      gl2lds(Ak + goff[q], ldsA + q * 1024);
      gl2lds(Bk + goff[q], ldsB + q * 1024);
    }
    __syncthreads();
#pragma unroll
    for (int ks = 0; ks < 2; ks++) {
      int co = ((quad + ks * 4) ^ ph) << 4;
      short8 af[4], bv[4];
#pragma unroll
      for (int mi = 0; mi < 4; mi++)
        af[mi] = *(const short8*)((const char*)Al + (wrow + mi*16 + m16) * 128 + co);
#pragma unroll
      for (int ni = 0; ni < 4; ni++)
        bv[ni] = *(const short8*)((const char*)Bl + (wcol + ni*16 + m16) * 128 + co);
#pragma unroll
      for (int mi = 0; mi < 4; mi++)
#pragma unroll
        for (int ni = 0; ni < 4; ni++)
          acc[mi][ni] = __builtin_amdgcn_mfma_f32_16x16x32_bf16(af[mi], bv[ni], acc[mi][ni], 0, 0, 0);
    }
    __syncthreads();
  }
#pragma unroll
  for (int mi = 0; mi < 4; mi++)
#pragma unroll
    for (int ni = 0; ni < 4; ni++)
#pragma unroll
      for (int r = 0; r < 4; r++) {
        int rl = wrow + mi*16 + quad*4 + r;
        if (M0 + rl < count) {
          int col = n0 + wcol + ni*16 + m16;
          Y[(size_t)(slot0 + rl) * DD + col] = acc[mi][ni][r];
        }
      }
}

// ---------------- per-slot LN_out stats ----------------
__global__ __launch_bounds__(256) void k_slotstats(
    const float* __restrict__ xf, const float* __restrict__ Y,
    const int* __restrict__ poffs, const int* __restrict__ counts,
    const int* __restrict__ slot_token, float* __restrict__ sstats)
{
  int s = blockIdx.x;
  int g = 0;
  while (g < NG - 1 && s >= poffs[g + 1]) g++;
  if (s - poffs[g] >= counts[g]) return;
  int t = slot_token[s];
  int d = threadIdx.x * 4;
  float4 yv = *(const float4*)(Y + (size_t)s*DD + d);
  float4 xv = *(const float4*)(xf + (size_t)t*DD + d);
  float z0 = xv.x + yv.x, z1 = xv.y + yv.y, z2 = xv.z + yv.z, z3 = xv.w + yv.w;
  float s1 = z0 + z1 + z2 + z3;
  float s2 = z0*z0 + z1*z1 + z2*z2 + z3*z3;
#pragma unroll
  for (int m = 32; m >= 1; m >>= 1) { s1 += __shfl_xor(s1, m); s2 += __shfl_xor(s2, m); }
  __shared__ float red[8];
  int wave = threadIdx.x >> 6, lane = threadIdx.x & 63;
  if (lane == 0) { red[wave*2] = s1; red[wave*2 + 1] = s2; }
  __syncthreads();
  if (threadIdx.x == 0) {
    float a = red[0] + red[2] + red[4] + red[6];
    float b = red[1] + red[3] + red[5] + red[7];
    float mean = a / DD;
    float var  = b / DD - mean * mean;
    sstats[s*2]   = mean;
    sstats[s*2+1] = rsqrtf(var + EPSV);
  }
}

// ---------------- final combine ----------------
__global__ __launch_bounds__(256) void k_final(
    const float* __restrict__ xf, const float* __restrict__ Y,
    const float* __restrict__ sstats, const int* __restrict__ inv_slot,
    const float* __restrict__ gate, const float* __restrict__ coefs,
    const float* __restrict__ lout_g, const float* __restrict__ lout_b,
    const float* __restrict__ cln_g, const float* __restrict__ cln_b,
    float* __restrict__ out)
{
  int t = blockIdx.x;
  int d = threadIdx.x * 4;
  int wave = threadIdx.x >> 6, lane = threadIdx.x & 63;
  float4 xv = *(const float4*)(xf + (size_t)t*DD + d);
  float4 o = {0.f, 0.f, 0.f, 0.f};
  __shared__ float red[8];
  for (int c = 0; c < 4; c++) {
    float gt = gate[t*4 + c];
    if (gt == 0.f) continue;
    float a0 = 0.f, a1 = 0.f, a2 = 0.f, a3 = 0.f;
    for (int e = 0; e < 4; e++) {
      float cf = coefs[t*16 + c*4 + e];
      if (cf <= 0.f) continue;
      int g = c*4 + e;
      int s = inv_slot[t*16 + g];
      float4 yv = *(const float4*)(Y + (size_t)s*DD + d);
      float mean = sstats[s*2], rstd = sstats[s*2+1];
      float4 gg = *(const float4*)(lout_g + (size_t)g*DD + d);
      float4 bb = *(const float4*)(lout_b + (size_t)g*DD + d);
      a0 += cf * ((xv.x + yv.x - mean)*rstd*gg.x + bb.x);
      a1 += cf * ((xv.y + yv.y - mean)*rstd*gg.y + bb.y);
      a2 += cf * ((xv.z + yv.z - mean)*rstd*gg.z + bb.z);
      a3 += cf * ((xv.w + yv.w - mean)*rstd*gg.w + bb.w);
    }
    float s1 = a0 + a1 + a2 + a3;
    float s2 = a0*a0 + a1*a1 + a2*a2 + a3*a3;
#pragma unroll
    for (int m = 32; m >= 1; m >>= 1) { s1 += __shfl_xor(s1, m); s2 += __shfl_xor(s2, m); }
    if (lane == 0) { red[wave*2] = s1; red[wave*2 + 1] = s2; }
    __syncthreads();
    float ts1 = red[0] + red[2] + red[4] + red[6];
    float ts2 = red[1] + red[3] + red[5] + red[7];
    __syncthreads();
    float mean = ts1 / DD;
    float rstd = rsqrtf(ts2 / DD - mean*mean + EPSV);
    float4 cg = *(const float4*)(cln_g + (size_t)c*DD + d);
    float4 cb = *(const float4*)(cln_b + (size_t)c*DD + d);
    o.x += gt * ((a0 - mean)*rstd*cg.x + cb.x);
    o.y += gt * ((a1 - mean)*rstd*cg.y + cb.y);
    o.z += gt * ((a2 - mean)*rstd*cg.z + cb.z);
    o.w += gt * ((a3 - mean)*rstd*cg.w + cb.w);
  }
  *(float4*)(out + (size_t)t*DD + d) = o;
}

extern "C" void kernel_launch(void* const* d_in, const int* in_sizes, int n_in,
                              void* d_out, int out_size, void* d_ws, size_t ws_size,
                              hipStream_t stream) {
  (void)in_sizes; (void)n_in; (void)out_size; (void)ws_size;
  const float* x      = (const float*)d_in[0];
  const float* W1     = (const float*)d_in[1];
  const float* W2     = (const float*)d_in[2];
  const float* W3     = (const float*)d_in[3];
  const float* lin_g  = (const float*)d_in[4];
  const float* lin_b  = (const float*)d_in[5];
  const float* lout_g = (const float*)d_in[6];
  const float* lout_b = (const float*)d_in[7];
  const float* cln_g  = (const float*)d_in[8];
  const float* cln_b  = (const float*)d_in[9];
  const float* Wrc    = (const float*)d_in[10];
  const float* brc    = (const float*)d_in[11];
  const float* Wre    = (const float*)d_in[12];
  const float* bre    = (const float*)d_in[13];
  float* out = (float*)d_out;
  char* ws = (char*)d_ws;

  int*   counts     = (int*)(ws + 0);
  int*   cursor     = (int*)(ws + 64);
  int*   poffs      = (int*)(ws + 128);
  float* gate       = (float*)(ws + 256);
  float* coefs      = (float*)(ws + 33024);
  float* tstats     = (float*)(ws + 164096);
  int*   slot_token = (int*)(ws + 180480);
  int*   inv_slot   = (int*)(ws + 221440);
  float* sstats     = (float*)(ws + 352512);
  unsigned short* Xgp = (unsigned short*)(ws + 1048576);    // 20 MiB [16][PSLOT][64]
  unsigned short* Hp  = (unsigned short*)(ws + 22020096);   // 40 MiB [32][PSLOT][64]
  unsigned short* W1p = (unsigned short*)(ws + 67108864);   // 64 MiB
  float*          Y   = (float*)(ws + 67108864);            // aliases W1p (dead after gemm1)
  unsigned short* W2p = (unsigned short*)(ws + 134217728);  // 32 MiB
  unsigned short* W3p = (unsigned short*)(ws + 167772160);  // 64 MiB -> total ~224 MiB

  hipMemsetAsync(ws, 0, 256, stream);
  hipMemsetAsync(ws + 256, 0, 163840, stream);

  k_pack<<<dim3(FF/64, DD/64, 16), 256, 0, stream>>>(W1, W1p, DD, FF, 0);
  k_pack<<<dim3(FF/64, DD/64,  8), 256, 0, stream>>>(W2, W2p, DD, FF, 1);
  k_pack<<<dim3(DD/64, FF/64, 16), 256, 0, stream>>>(W3, W3p, FF, DD, 0);

  k_route<<<TT, 256, 0, stream>>>(x, Wrc, brc, Wre, bre, gate, coefs, tstats, counts);
  k_offsets<<<1, 64, 0, stream>>>(counts, poffs);
  k_fill<<<(TT*NG)/256, 256, 0, stream>>>(coefs, poffs, cursor, slot_token, inv_slot);
  k_gather<<<PSLOT, 256, 0, stream>>>(x, tstats, lin_g, lin_b, poffs, counts, slot_token, Xgp);
  k_gemm1<true ><<<dim3(64, 4, 8), 256, 0, stream>>>(Xgp, W1p, W2p, counts, poffs, Hp);
  k_gemm1<false><<<dim3(64, 4, 8), 256, 0, stream>>>(Xgp, W1p, W2p, counts, poffs, Hp);
  k_gemm2<<<dim3(32, 4, 16), 256, 0, stream>>>(Hp, W3p, counts, poffs, Y);
  k_slotstats<<<PSLOT, 256, 0, stream>>>(x, Y, poffs, counts, slot_token, sstats);
  k_final<<<TT, 256, 0, stream>>>(x, Y, sstats, inv_slot, gate, coefs,
                                  lout_g, lout_b, cln_g, cln_b, out);
}

// Round 4
// 746.949 us; speedup vs baseline: 1.8039x; 1.0828x over previous
//
#include <hip/hip_runtime.h>
#include <cstdint>
#include <cstddef>

#define TT 2048
#define DD 1024
#define FF 2048
#define NG 16
#define PSLOT 10240
#define EPSV 1e-5f

typedef __attribute__((ext_vector_type(8))) short short8;
typedef __attribute__((ext_vector_type(4))) float floatx4;

__device__ inline unsigned short f2bf(float f) {
  union { float f; unsigned int u; } v; v.f = f;
  unsigned int r = v.u + 0x7fffu + ((v.u >> 16) & 1u);
  return (unsigned short)(r >> 16);
}

__device__ __forceinline__ void gl2lds(const void* g, void* l) {
  __builtin_amdgcn_global_load_lds(
      (const __attribute__((address_space(1))) void*)g,
      (__attribute__((address_space(3))) void*)l, 16, 0, 0);
}

// ---------------- routing ----------------
__global__ __launch_bounds__(256) void k_route(
    const float* __restrict__ xf, const float* __restrict__ Wrc,
    const float* __restrict__ brc, const float* __restrict__ Wre,
    const float* __restrict__ bre, float* __restrict__ gate,
    float* __restrict__ coefs, float* __restrict__ tstats,
    int* __restrict__ counts)
{
  int t = blockIdx.x;
  const float* xr = xf + (size_t)t * DD;
  float v[22];
#pragma unroll
  for (int i = 0; i < 22; i++) v[i] = 0.f;
  for (int d = threadIdx.x; d < DD; d += 256) {
    float x = xr[d];
    v[20] += x; v[21] += x * x;
    float4 wc = *(const float4*)(Wrc + (size_t)d * 4);
    v[0] += x * wc.x; v[1] += x * wc.y; v[2] += x * wc.z; v[3] += x * wc.w;
#pragma unroll
    for (int c = 0; c < 4; c++) {
      float4 we = *(const float4*)(Wre + ((size_t)c * DD + d) * 4);
      v[4 + c*4 + 0] += x * we.x; v[4 + c*4 + 1] += x * we.y;
      v[4 + c*4 + 2] += x * we.z; v[4 + c*4 + 3] += x * we.w;
    }
  }
#pragma unroll
  for (int m = 32; m >= 1; m >>= 1)
#pragma unroll
    for (int i = 0; i < 22; i++) v[i] += __shfl_xor(v[i], m);
  __shared__ float red[4][22];
  int wave = threadIdx.x >> 6, lane = threadIdx.x & 63;
  if (lane == 0) for (int i = 0; i < 22; i++) red[wave][i] = v[i];
  __syncthreads();
  if (threadIdx.x == 0) {
    for (int i = 0; i < 22; i++) v[i] = red[0][i] + red[1][i] + red[2][i] + red[3][i];
    float mean = v[20] / DD;
    float var  = v[21] / DD - mean * mean;
    tstats[t*2]   = mean;
    tstats[t*2+1] = rsqrtf(var + EPSV);
    float p[4]; float mx = -1e30f;
    for (int c = 0; c < 4; c++) { v[c] += brc[c]; mx = fmaxf(mx, v[c]); }
    for (int c = 0; c < 4; c++) p[c] = expf(v[c] - mx);
    int c0 = 0;
    for (int c = 1; c < 4; c++) if (p[c] > p[c0]) c0 = c;
    int c1 = (c0 == 0) ? 1 : 0;
    for (int c = 0; c < 4; c++) if (c != c0 && p[c] > p[c1]) c1 = c;
    float ws = p[c0] + p[c1];
    gate[t*4 + c0] = p[c0] / ws;
    gate[t*4 + c1] = p[c1] / ws;
    int sels[2] = {c0, c1};
    for (int si = 0; si < 2; si++) {
      int c = sels[si];
      float l[4];
      for (int e = 0; e < 4; e++) l[e] = v[4 + c*4 + e] + bre[c*4 + e];
      int e0 = 0;
      for (int e = 1; e < 4; e++) if (l[e] > l[e0]) e0 = e;
      int e1 = (e0 == 0) ? 1 : 0;
      for (int e = 0; e < 4; e++) if (e != e0 && l[e] > l[e1]) e1 = e;
      float q1 = expf(l[e1] - l[e0]);
      float r0 = 1.f / (1.f + q1);
      float r1 = q1 / (1.f + q1);
      if (r0 > 0.f) { coefs[t*16 + c*4 + e0] = r0; atomicAdd(&counts[c*4 + e0], 1); }
      if (r1 > 0.f) { coefs[t*16 + c*4 + e1] = r1; atomicAdd(&counts[c*4 + e1], 1); }
    }
  }
}

__global__ void k_offsets(const int* __restrict__ counts, int* __restrict__ poffs) {
  if (threadIdx.x == 0 && blockIdx.x == 0) {
    int s = 0;
    for (int i = 0; i < NG; i++) { poffs[i] = s; s += (counts[i] + 127) & ~127; }
    poffs[NG] = s;
  }
}

__global__ __launch_bounds__(256) void k_fill(
    const float* __restrict__ coefs, const int* __restrict__ poffs,
    int* __restrict__ cursor, int* __restrict__ slot_token, int* __restrict__ inv_slot)
{
  int idx = blockIdx.x * 256 + threadIdx.x;
  if (idx >= TT * NG) return;
  int t = idx >> 4, ce = idx & 15;
  if (coefs[idx] > 0.f) {
    int pos = atomicAdd(&cursor[ce], 1);
    int s = poffs[ce] + pos;
    slot_token[s] = t;
    inv_slot[idx] = s;
  }
}

// ---------------- weight pack: [K][N] fp32 -> [K/32][NV][32] bf16 ----------------
// mode 0: gs=gd, v=n           (plain)
// mode 1: gs=single-expert(gd), v=n        (W1 for gelu/relu groups)
// mode 2: gs=dual-expert(gd),  v=(n>>6)*128+(n&63)      (W1 half of W12)
// mode 3: gs=dual-expert(gd),  v=(n>>6)*128+64+(n&63)   (W2 half of W12)
__global__ __launch_bounds__(256) void k_pack(
    const float* __restrict__ src, unsigned short* __restrict__ dst,
    int K, int N, int NV, int mode)
{
  int gd = blockIdx.z;
  int gs;
  if (mode == 0) gs = gd;
  else if (mode == 1) gs = (gd >> 1) * 4 + 1 + (gd & 1);
  else gs = (gd >> 1) * 4 + ((gd & 1) ? 3 : 0);
  const float* S = src + (size_t)gs * K * N;
  unsigned short* D = dst + (size_t)gd * K * NV;
  int k0 = blockIdx.y * 64, nb = blockIdx.x * 64;
  int vb = (mode >= 2) ? ((nb >> 6) * 128 + ((mode == 3) ? 64 : 0)) : nb;
  __shared__ float T[64][65];
  int r0 = threadIdx.x >> 4, c4 = (threadIdx.x & 15) * 4;
#pragma unroll
  for (int r = 0; r < 4; r++) {
    int row = r0 + 16 * r;
    float4 v = *(const float4*)(S + (size_t)(k0 + row) * N + nb + c4);
    T[row][c4] = v.x; T[row][c4+1] = v.y; T[row][c4+2] = v.z; T[row][c4+3] = v.w;
  }
  __syncthreads();
#pragma unroll
  for (int r = 0; r < 4; r++) {
    int nrow = r0 + 16 * r;
    ushort4 o;
    o.x = f2bf(T[c4+0][nrow]); o.y = f2bf(T[c4+1][nrow]);
    o.z = f2bf(T[c4+2][nrow]); o.w = f2bf(T[c4+3][nrow]);
    size_t off = (size_t)((k0 + c4) >> 5) * ((size_t)NV * 32)
               + (size_t)(vb + nrow) * 32 + (c4 & 31);
    *(ushort4*)(D + off) = o;
  }
}

// ---------------- gather + LN_in -> packed bf16 [DD/32][PSLOT][32] ----------------
__global__ __launch_bounds__(256) void k_gather(
    const float* __restrict__ xf, const float* __restrict__ tstats,
    const float* __restrict__ lin_g, const float* __restrict__ lin_b,
    const int* __restrict__ poffs, const int* __restrict__ counts,
    const int* __restrict__ slot_token, unsigned short* __restrict__ Xgp)
{
  int s = blockIdx.x;
  int g = 0;
  while (g < NG - 1 && s >= poffs[g + 1]) g++;
  if (s - poffs[g] >= counts[g]) return;
  int t = slot_token[s];
  float mean = tstats[t*2], rstd = tstats[t*2+1];
  int d = threadIdx.x * 4;
  float4 x  = *(const float4*)(xf + (size_t)t*DD + d);
  float4 gg = *(const float4*)(lin_g + (size_t)g*DD + d);
  float4 bb = *(const float4*)(lin_b + (size_t)g*DD + d);
  ushort4 o;
  o.x = f2bf((x.x - mean)*rstd*gg.x + bb.x);
  o.y = f2bf((x.y - mean)*rstd*gg.y + bb.y);
  o.z = f2bf((x.z - mean)*rstd*gg.z + bb.z);
  o.w = f2bf((x.w - mean)*rstd*gg.w + bb.w);
  *(ushort4*)(Xgp + (size_t)(d >> 5) * (PSLOT * 32) + (size_t)s * 32 + (d & 31)) = o;
}

// ---------------- GEMM1 (unified): Xgp @ W -> act -> Hp packed ----------------
// dual groups (e in {0,3}): B tile = [64 W1-cols | 64 W2-cols], 32 n-tiles
// single groups (e in {1,2}): B tile = 128 W1-cols, 16 n-tiles
__global__ __launch_bounds__(256, 4) void k_gemm1(
    const unsigned short* __restrict__ Xgp, const unsigned short* __restrict__ W1sp,
    const unsigned short* __restrict__ W12p, const int* __restrict__ counts,
    const int* __restrict__ poffs, unsigned short* __restrict__ Hp)
{
  int g = blockIdx.z;
  int e = g & 3, c = g >> 2;
  bool dual = (e == 0 || e == 3);
  int nt = blockIdx.x;
  if (!dual && nt >= 16) return;
  int count = counts[g];
  int M0 = blockIdx.y * 128;
  if (M0 >= count) return;
  int slot0 = poffs[g] + M0;

  __shared__ char smem[32768];
  char* Al = smem;           // [2][8192]
  char* Bl = smem + 16384;   // [2][8192]

  const char* Ab = (const char*)(Xgp + (size_t)slot0 * 32);
  const char* Bb;
  size_t bslab;
  if (dual) {
    int d2 = c * 2 + (e ? 1 : 0);
    Bb = (const char*)(W12p + (size_t)d2 * DD * (2 * FF) + (size_t)nt * 128 * 32);
    bslab = (size_t)(2 * FF) * 64;
  } else {
    int s2 = c * 2 + (e - 1);
    Bb = (const char*)(W1sp + (size_t)s2 * DD * FF + (size_t)nt * 128 * 32);
    bslab = (size_t)FF * 64;
  }
  const size_t aslab = (size_t)PSLOT * 64;

  int tid = threadIdx.x, lane = tid & 63, wv = tid >> 6;
  int m16 = lane & 15, quad = lane >> 4;
  int wrow = (wv >> 1) * 64, wcol = (wv & 1) * 64;
  int chunk0 = wv * 2048, chunk1 = chunk0 + 1024;
  int lo = lane * 16;

  floatx4 zero4 = {0.f, 0.f, 0.f, 0.f};
  floatx4 acc[4][4];
#pragma unroll
  for (int i = 0; i < 4; i++)
#pragma unroll
    for (int j = 0; j < 4; j++) acc[i][j] = zero4;

  for (int it = 0; it < DD / 64; it++) {
    int kb = it * 2;
#pragma unroll
    for (int j = 0; j < 2; j++) {
      const char* Aj = Ab + (size_t)(kb + j) * aslab;
      const char* Bj = Bb + (size_t)(kb + j) * bslab;
      gl2lds(Aj + chunk0 + lo, Al + j * 8192 + chunk0);
      gl2lds(Aj + chunk1 + lo, Al + j * 8192 + chunk1);
      gl2lds(Bj + chunk0 + lo, Bl + j * 8192 + chunk0);
      gl2lds(Bj + chunk1 + lo, Bl + j * 8192 + chunk1);
    }
    __syncthreads();
#pragma unroll
    for (int j = 0; j < 2; j++) {
      short8 af[4], bv[4];
#pragma unroll
      for (int mi = 0; mi < 4; mi++)
        af[mi] = *(const short8*)(Al + j*8192 + (wrow + mi*16 + m16) * 64 + quad * 16);
#pragma unroll
      for (int ni = 0; ni < 4; ni++)
        bv[ni] = *(const short8*)(Bl + j*8192 + (wcol + ni*16 + m16) * 64 + quad * 16);
#pragma unroll
      for (int mi = 0; mi < 4; mi++)
#pragma unroll
        for (int ni = 0; ni < 4; ni++)
          acc[mi][ni] = __builtin_amdgcn_mfma_f32_16x16x32_bf16(af[mi], bv[ni], acc[mi][ni], 0, 0, 0);
    }
    __syncthreads();
  }

  if (dual) {
    float* ex = (float*)smem;  // [128][64] fp32 = 32 KB (A/B dead)
    if (wv & 1) {  // h2 (W2) waves
#pragma unroll
      for (int mi = 0; mi < 4; mi++)
#pragma unroll
        for (int ni = 0; ni < 4; ni++)
#pragma unroll
          for (int r = 0; r < 4; r++) {
            int row = wrow + mi*16 + quad*4 + r;
            ex[row * 64 + ni*16 + m16] = acc[mi][ni][r];
          }
    }
    __syncthreads();
    if (!(wv & 1)) {  // h1 (W1) waves
#pragma unroll
      for (int mi = 0; mi < 4; mi++)
#pragma unroll
        for (int ni = 0; ni < 4; ni++)
#pragma unroll
          for (int r = 0; r < 4; r++) {
            int row = wrow + mi*16 + quad*4 + r;
            if (M0 + row < count) {
              int cl = ni*16 + m16;
              float h1 = acc[mi][ni][r];
              float h2 = ex[row * 64 + cl];
              float sil = h2 / (1.f + expf(-h2));
              float h = sil * h2 * h1;
              int col = nt * 64 + cl;
              Hp[(size_t)(col >> 5) * (PSLOT * 32) + (size_t)(slot0 + row) * 32 + (col & 31)] = f2bf(h);
            }
          }
    }
  } else {
#pragma unroll
    for (int mi = 0; mi < 4; mi++)
#pragma unroll
      for (int ni = 0; ni < 4; ni++)
#pragma unroll
        for (int r = 0; r < 4; r++) {
          int row = wrow + mi*16 + quad*4 + r;
          if (M0 + row < count) {
            int col = nt * 128 + wcol + ni*16 + m16;
            float h1 = acc[mi][ni][r];
            float h;
            if (e == 1) h = 0.5f * h1 * (1.f + erff(h1 * 0.70710678118f));
            else        h = fmaxf(h1, 0.f);
            Hp[(size_t)(col >> 5) * (PSLOT * 32) + (size_t)(slot0 + row) * 32 + (col & 31)] = f2bf(h);
          }
        }
  }
}

// ---------------- GEMM2: Hp @ W3p -> Y (fp32, natural rows), 128x64 tiles ----------------
__global__ __launch_bounds__(256, 4) void k_gemm2(
    const unsigned short* __restrict__ Hp, const unsigned short* __restrict__ W3p,
    const int* __restrict__ counts, const int* __restrict__ poffs,
    float* __restrict__ Y)
{
  int g = blockIdx.z;
  int count = counts[g];
  int M0 = blockIdx.y * 128;
  if (M0 >= count) return;
  int nt = blockIdx.x;  // 0..15 (64 cols each)
  int slot0 = poffs[g] + M0;
  __shared__ char smem[24576];
  char* Al = smem;           // [2][8192]
  char* Bl = smem + 16384;   // [2][4096]
  const char* Ab = (const char*)(Hp + (size_t)slot0 * 32);
  const char* Bb = (const char*)(W3p + (size_t)g * FF * DD + (size_t)nt * 64 * 32);
  const size_t aslab = (size_t)PSLOT * 64;
  const size_t bslab = (size_t)DD * 64;
  int tid = threadIdx.x, lane = tid & 63, wv = tid >> 6;
  int m16 = lane & 15, quad = lane >> 4;
  int wrow = (wv >> 1) * 64, wcol = (wv & 1) * 32;
  int chunk0 = wv * 2048, chunk1 = chunk0 + 1024;
  int bchunk = wv * 1024;
  int lo = lane * 16;
  floatx4 zero4 = {0.f, 0.f, 0.f, 0.f};
  floatx4 acc[4][2];
#pragma unroll
  for (int i = 0; i < 4; i++) { acc[i][0] = zero4; acc[i][1] = zero4; }
  for (int it = 0; it < FF / 64; it++) {
    int kb = it * 2;
#pragma unroll
    for (int j = 0; j < 2; j++) {
      const char* Aj = Ab + (size_t)(kb + j) * aslab;
      const char* Bj = Bb + (size_t)(kb + j) * bslab;
      gl2lds(Aj + chunk0 + lo, Al + j * 8192 + chunk0);
      gl2lds(Aj + chunk1 + lo, Al + j * 8192 + chunk1);
      gl2lds(Bj + bchunk + lo, Bl + j * 4096 + bchunk);
    }
    __syncthreads();
#pragma unroll
    for (int j = 0; j < 2; j++) {
      short8 af[4], bv[2];
#pragma unroll
      for (int mi = 0; mi < 4; mi++)
        af[mi] = *(const short8*)(Al + j*8192 + (wrow + mi*16 + m16) * 64 + quad * 16);
#pragma unroll
      for (int ni = 0; ni < 2; ni++)
        bv[ni] = *(const short8*)(Bl + j*4096 + (wcol + ni*16 + m16) * 64 + quad * 16);
#pragma unroll
      for (int mi = 0; mi < 4; mi++)
#pragma unroll
        for (int ni = 0; ni < 2; ni++)
          acc[mi][ni] = __builtin_amdgcn_mfma_f32_16x16x32_bf16(af[mi], bv[ni], acc[mi][ni], 0, 0, 0);
    }
    __syncthreads();
  }
#pragma unroll
  for (int mi = 0; mi < 4; mi++)
#pragma unroll
    for (int ni = 0; ni < 2; ni++)
#pragma unroll
      for (int r = 0; r < 4; r++) {
        int row = wrow + mi*16 + quad*4 + r;
        if (M0 + row < count)
          Y[(size_t)(slot0 + row) * DD + nt*64 + wcol + ni*16 + m16] = acc[mi][ni][r];
      }
}

// ---------------- per-slot LN_out stats ----------------
__global__ __launch_bounds__(256) void k_slotstats(
    const float* __restrict__ xf, const float* __restrict__ Y,
    const int* __restrict__ poffs, const int* __restrict__ counts,
    const int* __restrict__ slot_token, float* __restrict__ sstats)
{
  int s = blockIdx.x;
  int g = 0;
  while (g < NG - 1 && s >= poffs[g + 1]) g++;
  if (s - poffs[g] >= counts[g]) return;
  int t = slot_token[s];
  int d = threadIdx.x * 4;
  float4 yv = *(const float4*)(Y + (size_t)s*DD + d);
  float4 xv = *(const float4*)(xf + (size_t)t*DD + d);
  float z0 = xv.x + yv.x, z1 = xv.y + yv.y, z2 = xv.z + yv.z, z3 = xv.w + yv.w;
  float s1 = z0 + z1 + z2 + z3;
  float s2 = z0*z0 + z1*z1 + z2*z2 + z3*z3;
#pragma unroll
  for (int m = 32; m >= 1; m >>= 1) { s1 += __shfl_xor(s1, m); s2 += __shfl_xor(s2, m); }
  __shared__ float red[8];
  int wave = threadIdx.x >> 6, lane = threadIdx.x & 63;
  if (lane == 0) { red[wave*2] = s1; red[wave*2 + 1] = s2; }
  __syncthreads();
  if (threadIdx.x == 0) {
    float a = red[0] + red[2] + red[4] + red[6];
    float b = red[1] + red[3] + red[5] + red[7];
    float mean = a / DD;
    float var  = b / DD - mean * mean;
    sstats[s*2]   = mean;
    sstats[s*2+1] = rsqrtf(var + EPSV);
  }
}

// ---------------- final combine ----------------
__global__ __launch_bounds__(256) void k_final(
    const float* __restrict__ xf, const float* __restrict__ Y,
    const float* __restrict__ sstats, const int* __restrict__ inv_slot,
    const float* __restrict__ gate, const float* __restrict__ coefs,
    const float* __restrict__ lout_g, const float* __restrict__ lout_b,
    const float* __restrict__ cln_g, const float* __restrict__ cln_b,
    float* __restrict__ out)
{
  int t = blockIdx.x;
  int d = threadIdx.x * 4;
  int wave = threadIdx.x >> 6, lane = threadIdx.x & 63;
  float4 xv = *(const float4*)(xf + (size_t)t*DD + d);
  float4 o = {0.f, 0.f, 0.f, 0.f};
  __shared__ float red[8];
  for (int c = 0; c < 4; c++) {
    float gt = gate[t*4 + c];
    if (gt == 0.f) continue;
    float a0 = 0.f, a1 = 0.f, a2 = 0.f, a3 = 0.f;
    for (int e = 0; e < 4; e++) {
      float cf = coefs[t*16 + c*4 + e];
      if (cf <= 0.f) continue;
      int g = c*4 + e;
      int s = inv_slot[t*16 + g];
      float4 yv = *(const float4*)(Y + (size_t)s*DD + d);
      float mean = sstats[s*2], rstd = sstats[s*2+1];
      float4 gg = *(const float4*)(lout_g + (size_t)g*DD + d);
      float4 bb = *(const float4*)(lout_b + (size_t)g*DD + d);
      a0 += cf * ((xv.x + yv.x - mean)*rstd*gg.x + bb.x);
      a1 += cf * ((xv.y + yv.y - mean)*rstd*gg.y + bb.y);
      a2 += cf * ((xv.z + yv.z - mean)*rstd*gg.z + bb.z);
      a3 += cf * ((xv.w + yv.w - mean)*rstd*gg.w + bb.w);
    }
    float s1 = a0 + a1 + a2 + a3;
    float s2 = a0*a0 + a1*a1 + a2*a2 + a3*a3;
#pragma unroll
    for (int m = 32; m >= 1; m >>= 1) { s1 += __shfl_xor(s1, m); s2 += __shfl_xor(s2, m); }
    if (lane == 0) { red[wave*2] = s1; red[wave*2 + 1] = s2; }
    __syncthreads();
    float ts1 = red[0] + red[2] + red[4] + red[6];
    float ts2 = red[1] + red[3] + red[5] + red[7];
    __syncthreads();
    float mean = ts1 / DD;
    float rstd = rsqrtf(ts2 / DD - mean*mean + EPSV);
    float4 cg = *(const float4*)(cln_g + (size_t)c*DD + d);
    float4 cb = *(const float4*)(cln_b + (size_t)c*DD + d);
    o.x += gt * ((a0 - mean)*rstd*cg.x + cb.x);
    o.y += gt * ((a1 - mean)*rstd*cg.y + cb.y);
    o.z += gt * ((a2 - mean)*rstd*cg.z + cb.z);
    o.w += gt * ((a3 - mean)*rstd*cg.w + cb.w);
  }
  *(float4*)(out + (size_t)t*DD + d) = o;
}

extern "C" void kernel_launch(void* const* d_in, const int* in_sizes, int n_in,
                              void* d_out, int out_size, void* d_ws, size_t ws_size,
                              hipStream_t stream) {
  (void)in_sizes; (void)n_in; (void)out_size; (void)ws_size;
  const float* x      = (const float*)d_in[0];
  const float* W1     = (const float*)d_in[1];
  const float* W2     = (const float*)d_in[2];
  const float* W3     = (const float*)d_in[3];
  const float* lin_g  = (const float*)d_in[4];
  const float* lin_b  = (const float*)d_in[5];
  const float* lout_g = (const float*)d_in[6];
  const float* lout_b = (const float*)d_in[7];
  const float* cln_g  = (const float*)d_in[8];
  const float* cln_b  = (const float*)d_in[9];
  const float* Wrc    = (const float*)d_in[10];
  const float* brc    = (const float*)d_in[11];
  const float* Wre    = (const float*)d_in[12];
  const float* bre    = (const float*)d_in[13];
  float* out = (float*)d_out;
  char* ws = (char*)d_ws;

  int*   counts     = (int*)(ws + 0);
  int*   cursor     = (int*)(ws + 64);
  int*   poffs      = (int*)(ws + 128);
  float* gate       = (float*)(ws + 256);
  float* coefs      = (float*)(ws + 33024);
  float* tstats     = (float*)(ws + 164096);
  int*   slot_token = (int*)(ws + 180480);
  int*   inv_slot   = (int*)(ws + 221440);
  float* sstats     = (float*)(ws + 352512);
  unsigned short* Xgp  = (unsigned short*)(ws + 1048576);    // 20 MiB [DD/32][PSLOT][32]
  unsigned short* Hp   = (unsigned short*)(ws + 22020096);   // 40 MiB [FF/32][PSLOT][32]
  unsigned short* W1sp = (unsigned short*)(ws + 63963136);   // 32 MiB, 8 single groups
  unsigned short* W12p = (unsigned short*)(ws + 97517568);   // 64 MiB, 8 dual groups interleaved
  float*          Y    = (float*)(ws + 97517568);            // aliases W12p (dead after gemm1)
  unsigned short* W3p  = (unsigned short*)(ws + 164626432);  // 64 MiB, 16 groups
  // total ~221 MiB

  hipMemsetAsync(ws, 0, 256, stream);
  hipMemsetAsync(ws + 256, 0, 163840, stream);

  k_pack<<<dim3(FF/64, DD/64,  8), 256, 0, stream>>>(W1, W1sp, DD, FF, FF,     1);
  k_pack<<<dim3(FF/64, DD/64,  8), 256, 0, stream>>>(W1, W12p, DD, FF, 2*FF,   2);
  k_pack<<<dim3(FF/64, DD/64,  8), 256, 0, stream>>>(W2, W12p, DD, FF, 2*FF,   3);
  k_pack<<<dim3(DD/64, FF/64, 16), 256, 0, stream>>>(W3, W3p,  FF, DD, DD,     0);

  k_route<<<TT, 256, 0, stream>>>(x, Wrc, brc, Wre, bre, gate, coefs, tstats, counts);
  k_offsets<<<1, 64, 0, stream>>>(counts, poffs);
  k_fill<<<(TT*NG)/256, 256, 0, stream>>>(coefs, poffs, cursor, slot_token, inv_slot);
  k_gather<<<PSLOT, 256, 0, stream>>>(x, tstats, lin_g, lin_b, poffs, counts, slot_token, Xgp);
  k_gemm1<<<dim3(32, 16, 16), 256, 0, stream>>>(Xgp, W1sp, W12p, counts, poffs, Hp);
  k_gemm2<<<dim3(16, 16, 16), 256, 0, stream>>>(Hp, W3p, counts, poffs, Y);
  k_slotstats<<<PSLOT, 256, 0, stream>>>(x, Y, poffs, counts, slot_token, sstats);
  k_final<<<TT, 256, 0, stream>>>(x, Y, sstats, inv_slot, gate, coefs,
                                  lout_g, lout_b, cln_g, cln_b, out);
}